// Round 2
// baseline (364.769 us; speedup 1.0000x reference)
//
#include <hip/hip_runtime.h>
#include <hip/hip_bf16.h>

// B=4, S=2048, D=512, H=8, DH=64
// Pipeline:
//  1. cast embed + weights to bf16
//  2. QKV projection GEMM (bf16 MFMA 16x16x32), V stored transposed [B,H,DH,S]
//  3. suffix sums of V at 16-granularity (for the "tril zeros feed softmax" quirk)
//  4. flash attention with online softmax; masked-in-region entries included as x=0,
//     trailing masked region folded in analytically via SUF
//  5. Wo GEMM + bias + residual (f32 out)
//  6. LayerNorm

typedef __bf16 bf16;
typedef __bf16 bf16x8 __attribute__((ext_vector_type(8)));
typedef __bf16 bf16x4v __attribute__((ext_vector_type(4)));
typedef float f32x4 __attribute__((ext_vector_type(4)));

#define S_LEN 2048
#define DMODEL 512
#define INV_SQRT_D 0.044194173824159216f  // 1/sqrt(512)

__global__ __launch_bounds__(256) void cast_f32_bf16(const float* __restrict__ in,
                                                     bf16* __restrict__ out, int n4) {
  int i = blockIdx.x * blockDim.x + threadIdx.x;
  if (i < n4) {
    float4 v = reinterpret_cast<const float4*>(in)[i];
    bf16x4v o;
    o[0] = (bf16)v.x; o[1] = (bf16)v.y; o[2] = (bf16)v.z; o[3] = (bf16)v.w;
    *reinterpret_cast<bf16x4v*>(out + (size_t)i * 4) = o;
  }
}

// C[M,N] = A[M,512] * W[N,512]^T + bias.  Tile 64x64, 4 waves, wave = 16 rows x 64 cols.
__global__ __launch_bounds__(256) void gemm_qkv(
    const bf16* __restrict__ A,
    const bf16* __restrict__ Wqb, const bf16* __restrict__ Wkb, const bf16* __restrict__ Wvb,
    const float* __restrict__ bq, const float* __restrict__ bk, const float* __restrict__ bv,
    bf16* __restrict__ Qb, bf16* __restrict__ Kb, bf16* __restrict__ Vt) {
  int z = blockIdx.z;
  const bf16* W = (z == 0) ? Wqb : (z == 1) ? Wkb : Wvb;
  const float* bias = (z == 0) ? bq : (z == 1) ? bk : bv;
  int tid = threadIdx.x;
  int w = tid >> 6, l = tid & 63, lr = l & 15, lg = l >> 4;
  int row0 = blockIdx.x * 64 + w * 16;
  int col0 = blockIdx.y * 64;
  f32x4 acc[4] = {};
  const bf16* Ap = A + (size_t)(row0 + lr) * DMODEL + lg * 8;
  const bf16* Wp = W + (size_t)(col0 + lr) * DMODEL + lg * 8;
  for (int kk = 0; kk < 16; ++kk) {
    bf16x8 a = *(const bf16x8*)(Ap + kk * 32);
#pragma unroll
    for (int c = 0; c < 4; ++c) {
      bf16x8 bfr = *(const bf16x8*)(Wp + (size_t)c * 16 * DMODEL + kk * 32);
      acc[c] = __builtin_amdgcn_mfma_f32_16x16x32_bf16(a, bfr, acc[c], 0, 0, 0);
    }
  }
  if (z < 2) {
    bf16* O = (z == 0) ? Qb : Kb;
#pragma unroll
    for (int c = 0; c < 4; ++c) {
      int cg = col0 + 16 * c + lr;
      float bi = bias[cg];
#pragma unroll
      for (int r = 0; r < 4; ++r) {
        int rg = row0 + lg * 4 + r;
        O[(size_t)rg * DMODEL + cg] = (bf16)(acc[c][r] + bi);
      }
    }
  } else {
    // V: store transposed -> Vt[b][h][e][s], 4 consecutive s per lane = one 8B store
    int h = blockIdx.y;            // col0 == h*64
    int b = row0 >> 11;
    int s0 = (row0 & 2047) + lg * 4;
#pragma unroll
    for (int c = 0; c < 4; ++c) {
      int e = 16 * c + lr;
      float bi = bias[col0 + e];
      bf16x4v pk;
#pragma unroll
      for (int r = 0; r < 4; ++r) pk[r] = (bf16)(acc[c][r] + bi);
      *(bf16x4v*)(Vt + ((size_t)((b * 8 + h) * 64 + e)) * S_LEN + s0) = pk;
    }
  }
}

// SUF[bh][j][e] = sum_{t >= 16j} V[t][e], j = 0..128 (SUF[128]=0)
__global__ void suf_kernel(const bf16* __restrict__ Vt, float* __restrict__ SUF) {
  int bh = blockIdx.x;
  int e = threadIdx.x;  // 64 threads
  const bf16* vrow = Vt + ((size_t)bh * 64 + e) * S_LEN;
  float* srow = SUF + (size_t)bh * 129 * 64 + e;
  srow[(size_t)128 * 64] = 0.f;
  float carry = 0.f;
  for (int j = 127; j >= 0; --j) {
    bf16x8 a = *(const bf16x8*)(vrow + j * 16);
    bf16x8 b2 = *(const bf16x8*)(vrow + j * 16 + 8);
    float s = 0.f;
#pragma unroll
    for (int k = 0; k < 8; ++k) s += (float)a[k] + (float)b2[k];
    carry += s;
    srow[(size_t)j * 64] = carry;
  }
}

__global__ __launch_bounds__(256) void flash_attn(
    const bf16* __restrict__ Qb, const bf16* __restrict__ Kb,
    const bf16* __restrict__ Vt, const float* __restrict__ SUF,
    bf16* __restrict__ attO) {
  int bh = blockIdx.y;
  int b = bh >> 3, h = bh & 7;
  int qb = blockIdx.x * 64;
  int tid = threadIdx.x;
  int w = tid >> 6, l = tid & 63, lr = l & 15, lg = l >> 4;

  __shared__ __align__(16) bf16 kl[32 * 72];      // K tile [32 t][64 e], pad 72
  __shared__ __align__(16) bf16 vl[64 * 40];      // V^T tile [64 e][32 t], pad 40
  __shared__ __align__(16) bf16 pl[4][16 * 40];   // per-wave P tile [16 s][32 t], pad 40

  int srow = qb + 16 * w + lr;
  const bf16* qptr = Qb + ((size_t)(b * S_LEN) + srow) * DMODEL + h * 64 + lg * 8;
  bf16x8 aq0 = *(const bf16x8*)(qptr);
  bf16x8 aq1 = *(const bf16x8*)(qptr + 32);

  float m[4] = {0.f, 0.f, 0.f, 0.f};   // init 0: masked entries are exact zeros
  float lsum[4] = {0.f, 0.f, 0.f, 0.f};
  f32x4 acc[4] = {};

  int tmax_w = qb + 16 * w + 16;       // this wave's accounting boundary (mult of 16)
  int tend = qb + 64;
  const bf16* Kbase = Kb + ((size_t)(b * S_LEN)) * DMODEL + h * 64;
  const bf16* Vbase = Vt + ((size_t)bh * 64) * S_LEN;

  int kr = tid >> 3, kc = (tid & 7) * 8;
  int ve = tid >> 2, vc = (tid & 3) * 8;

  for (int t0 = 0; t0 < tend; t0 += 32) {
    *(bf16x8*)&kl[kr * 72 + kc] = *(const bf16x8*)(Kbase + (size_t)(t0 + kr) * DMODEL + kc);
    *(bf16x8*)&vl[ve * 40 + vc] = *(const bf16x8*)(Vbase + (size_t)ve * S_LEN + t0 + vc);
    __syncthreads();

    f32x4 sfrag[2];
    const f32x4 fz = {0.f, 0.f, 0.f, 0.f};
#pragma unroll
    for (int c = 0; c < 2; ++c) {
      bf16x8 bk0 = *(const bf16x8*)&kl[(16 * c + lr) * 72 + lg * 8];
      bf16x8 bk1 = *(const bf16x8*)&kl[(16 * c + lr) * 72 + 32 + lg * 8];
      f32x4 t = __builtin_amdgcn_mfma_f32_16x16x32_bf16(aq0, bk0, fz, 0, 0, 0);
      sfrag[c] = __builtin_amdgcn_mfma_f32_16x16x32_bf16(aq1, bk1, t, 0, 0, 0);
    }

    float p[2][4];
#pragma unroll
    for (int r = 0; r < 4; ++r) {
      int sg = qb + 16 * w + lg * 4 + r;
      int tg0 = t0 + lr, tg1 = t0 + 16 + lr;
      float x0 = (tg0 <= sg) ? sfrag[0][r] * INV_SQRT_D : ((tg0 < tmax_w) ? 0.f : -1e30f);
      float x1 = (tg1 <= sg) ? sfrag[1][r] * INV_SQRT_D : ((tg1 < tmax_w) ? 0.f : -1e30f);
      float mx = fmaxf(x0, x1);
#pragma unroll
      for (int d = 1; d < 16; d <<= 1) mx = fmaxf(mx, __shfl_xor(mx, d, 64));
      float mn = fmaxf(m[r], mx);
      float sc = __expf(m[r] - mn);
      float p0 = __expf(x0 - mn), p1 = __expf(x1 - mn);
      float ls = p0 + p1;
#pragma unroll
      for (int d = 1; d < 16; d <<= 1) ls += __shfl_xor(ls, d, 64);
      lsum[r] = lsum[r] * sc + ls;
      m[r] = mn;
#pragma unroll
      for (int c = 0; c < 4; ++c) acc[c][r] *= sc;
      p[0][r] = p0; p[1][r] = p1;
    }

    // P -> LDS (C-frag layout) -> A-frag for PV
    bf16* pw = pl[w];
#pragma unroll
    for (int c = 0; c < 2; ++c)
#pragma unroll
      for (int r = 0; r < 4; ++r)
        pw[(lg * 4 + r) * 40 + 16 * c + lr] = (bf16)p[c][r];

    bf16x8 pa = *(const bf16x8*)&pw[lr * 40 + lg * 8];
#pragma unroll
    for (int c = 0; c < 4; ++c) {
      bf16x8 bv_ = *(const bf16x8*)&vl[(16 * c + lr) * 40 + lg * 8];
      acc[c] = __builtin_amdgcn_mfma_f32_16x16x32_bf16(pa, bv_, acc[c], 0, 0, 0);
    }
    __syncthreads();
  }

  // trailing masked region: count + V suffix sum, weight e^{-m}
  int j16 = tmax_w >> 4;
  const float* suf = SUF + ((size_t)bh * 129 + j16) * 64;
  float cnt = (float)(S_LEN - tmax_w);
  float sufe[4];
#pragma unroll
  for (int c = 0; c < 4; ++c) sufe[c] = suf[16 * c + lr];
#pragma unroll
  for (int r = 0; r < 4; ++r) {
    float em = __expf(-m[r]);
    float inv = 1.f / (lsum[r] + cnt * em);
    int sg = qb + 16 * w + lg * 4 + r;
#pragma unroll
    for (int c = 0; c < 4; ++c) {
      float o = (acc[c][r] + em * sufe[c]) * inv;
      attO[((size_t)(b * S_LEN) + sg) * DMODEL + h * 64 + 16 * c + lr] = (bf16)o;
    }
  }
}

__global__ __launch_bounds__(256) void gemm_wo(
    const bf16* __restrict__ A, const bf16* __restrict__ W,
    const float* __restrict__ bo, const float* __restrict__ embed,
    float* __restrict__ X) {
  int tid = threadIdx.x;
  int w = tid >> 6, l = tid & 63, lr = l & 15, lg = l >> 4;
  int row0 = blockIdx.x * 64 + w * 16;
  int col0 = blockIdx.y * 64;
  f32x4 acc[4] = {};
  const bf16* Ap = A + (size_t)(row0 + lr) * DMODEL + lg * 8;
  const bf16* Wp = W + (size_t)(col0 + lr) * DMODEL + lg * 8;
  for (int kk = 0; kk < 16; ++kk) {
    bf16x8 a = *(const bf16x8*)(Ap + kk * 32);
#pragma unroll
    for (int c = 0; c < 4; ++c) {
      bf16x8 bfr = *(const bf16x8*)(Wp + (size_t)c * 16 * DMODEL + kk * 32);
      acc[c] = __builtin_amdgcn_mfma_f32_16x16x32_bf16(a, bfr, acc[c], 0, 0, 0);
    }
  }
#pragma unroll
  for (int c = 0; c < 4; ++c) {
    int cg = col0 + 16 * c + lr;
    float bi = bo[cg];
#pragma unroll
    for (int r = 0; r < 4; ++r) {
      int rg = row0 + lg * 4 + r;
      X[(size_t)rg * DMODEL + cg] = acc[c][r] + bi + embed[(size_t)rg * DMODEL + cg];
    }
  }
}

__global__ __launch_bounds__(256) void ln_kernel(const float* __restrict__ x,
                                                 const float* __restrict__ gamma,
                                                 const float* __restrict__ beta,
                                                 float* __restrict__ out) {
  int row = blockIdx.x * 4 + (threadIdx.x >> 6);
  int l = threadIdx.x & 63;
  const float4* xr = reinterpret_cast<const float4*>(x + (size_t)row * DMODEL) + l * 2;
  float4 v0 = xr[0], v1 = xr[1];
  float s = v0.x + v0.y + v0.z + v0.w + v1.x + v1.y + v1.z + v1.w;
  float s2 = v0.x * v0.x + v0.y * v0.y + v0.z * v0.z + v0.w * v0.w +
             v1.x * v1.x + v1.y * v1.y + v1.z * v1.z + v1.w * v1.w;
#pragma unroll
  for (int d = 1; d < 64; d <<= 1) {
    s += __shfl_xor(s, d, 64);
    s2 += __shfl_xor(s2, d, 64);
  }
  float mean = s * (1.f / 512.f);
  float var = s2 * (1.f / 512.f) - mean * mean;
  float rstd = rsqrtf(var + 1e-5f);
  const float4* g4 = reinterpret_cast<const float4*>(gamma) + l * 2;
  const float4* b4 = reinterpret_cast<const float4*>(beta) + l * 2;
  float4 g0 = g4[0], g1 = g4[1], bb0 = b4[0], bb1 = b4[1];
  float4 o0, o1;
  o0.x = (v0.x - mean) * rstd * g0.x + bb0.x;
  o0.y = (v0.y - mean) * rstd * g0.y + bb0.y;
  o0.z = (v0.z - mean) * rstd * g0.z + bb0.z;
  o0.w = (v0.w - mean) * rstd * g0.w + bb0.w;
  o1.x = (v1.x - mean) * rstd * g1.x + bb1.x;
  o1.y = (v1.y - mean) * rstd * g1.y + bb1.y;
  o1.z = (v1.z - mean) * rstd * g1.z + bb1.z;
  o1.w = (v1.w - mean) * rstd * g1.w + bb1.w;
  float4* orow = reinterpret_cast<float4*>(out + (size_t)row * DMODEL) + l * 2;
  orow[0] = o0;
  orow[1] = o1;
}

extern "C" void kernel_launch(void* const* d_in, const int* in_sizes, int n_in,
                              void* d_out, int out_size, void* d_ws, size_t ws_size,
                              hipStream_t stream) {
  const float* embed = (const float*)d_in[0];
  const float* Wq = (const float*)d_in[1];
  const float* bq = (const float*)d_in[2];
  const float* Wk = (const float*)d_in[3];
  const float* bk = (const float*)d_in[4];
  const float* Wv = (const float*)d_in[5];
  const float* bv = (const float*)d_in[6];
  const float* Wo = (const float*)d_in[7];
  const float* bo = (const float*)d_in[8];
  const float* gamma = (const float*)d_in[9];
  const float* beta = (const float*)d_in[10];
  float* out = (float*)d_out;

  char* ws = (char*)d_ws;
  size_t off = 0;
  auto alc = [&](size_t b) { size_t o = off; off += (b + 255) & ~(size_t)255; return o; };
  bf16* Eb   = (bf16*)(ws + alc(8192ull * 512 * 2));
  bf16* Wqb  = (bf16*)(ws + alc(512ull * 512 * 2));
  bf16* Wkb  = (bf16*)(ws + alc(512ull * 512 * 2));
  bf16* Wvb  = (bf16*)(ws + alc(512ull * 512 * 2));
  bf16* Wob  = (bf16*)(ws + alc(512ull * 512 * 2));
  bf16* Qb   = (bf16*)(ws + alc(8192ull * 512 * 2));
  bf16* Kb   = (bf16*)(ws + alc(8192ull * 512 * 2));
  bf16* Vt   = (bf16*)(ws + alc(8192ull * 512 * 2));
  float* SUF = (float*)(ws + alc(32ull * 129 * 64 * 4));
  bf16* AttO = (bf16*)(ws + alc(8192ull * 512 * 2));
  float* Xb  = (float*)(ws + alc(8192ull * 512 * 4));
  (void)ws_size; (void)n_in; (void)in_sizes; (void)out_size;

  cast_f32_bf16<<<4096, 256, 0, stream>>>(embed, Eb, 4194304 / 4);
  cast_f32_bf16<<<256, 256, 0, stream>>>(Wq, Wqb, 262144 / 4);
  cast_f32_bf16<<<256, 256, 0, stream>>>(Wk, Wkb, 262144 / 4);
  cast_f32_bf16<<<256, 256, 0, stream>>>(Wv, Wvb, 262144 / 4);
  cast_f32_bf16<<<256, 256, 0, stream>>>(Wo, Wob, 262144 / 4);

  gemm_qkv<<<dim3(128, 8, 3), 256, 0, stream>>>(Eb, Wqb, Wkb, Wvb, bq, bk, bv, Qb, Kb, Vt);
  suf_kernel<<<32, 64, 0, stream>>>(Vt, SUF);
  flash_attn<<<dim3(32, 32), 256, 0, stream>>>(Qb, Kb, Vt, SUF, AttO);
  gemm_wo<<<dim3(128, 8), 256, 0, stream>>>(AttO, Wob, bo, embed, Xb);
  ln_kernel<<<2048, 256, 0, stream>>>(Xb, gamma, beta, out);
}

// Round 3
// 243.543 us; speedup vs baseline: 1.4978x; 1.4978x over previous
//
#include <hip/hip_runtime.h>
#include <hip/hip_bf16.h>

// B=4, S=2048, D=512, H=8, DH=64
// Flat-softmax flash attention: scores are analytically bounded (|x| < ~0.5),
// and tril() zeros (not -inf) pin the softmax max to ~0 -> no online max needed.
// p = exp(x), lsum accumulated per-lane, reduced once at the end.
// Masked tail handled analytically: numerator += SUF (V suffix sum), denom += count.

typedef __bf16 bf16;
typedef __bf16 bf16x8 __attribute__((ext_vector_type(8)));
typedef __bf16 bf16x4v __attribute__((ext_vector_type(4)));
typedef float f32x4 __attribute__((ext_vector_type(4)));

#define S_LEN 2048
#define DMODEL 512
#define INV_SQRT_D 0.044194173824159216f  // 1/sqrt(512), folded into Q at projection

__global__ __launch_bounds__(256) void cast_f32_bf16(const float* __restrict__ in,
                                                     bf16* __restrict__ out, int n4) {
  int i = blockIdx.x * blockDim.x + threadIdx.x;
  if (i < n4) {
    float4 v = reinterpret_cast<const float4*>(in)[i];
    bf16x4v o;
    o[0] = (bf16)v.x; o[1] = (bf16)v.y; o[2] = (bf16)v.z; o[3] = (bf16)v.w;
    *reinterpret_cast<bf16x4v*>(out + (size_t)i * 4) = o;
  }
}

// four 512x512 weight casts in one launch (blockIdx.y selects)
__global__ __launch_bounds__(256) void cast4_f32_bf16(
    const float* __restrict__ a0, const float* __restrict__ a1,
    const float* __restrict__ a2, const float* __restrict__ a3,
    bf16* __restrict__ o0, bf16* __restrict__ o1,
    bf16* __restrict__ o2, bf16* __restrict__ o3) {
  int y = blockIdx.y;
  const float* in = (y == 0) ? a0 : (y == 1) ? a1 : (y == 2) ? a2 : a3;
  bf16* out = (y == 0) ? o0 : (y == 1) ? o1 : (y == 2) ? o2 : o3;
  int i = blockIdx.x * blockDim.x + threadIdx.x;
  float4 v = reinterpret_cast<const float4*>(in)[i];
  bf16x4v o;
  o[0] = (bf16)v.x; o[1] = (bf16)v.y; o[2] = (bf16)v.z; o[3] = (bf16)v.w;
  *reinterpret_cast<bf16x4v*>(out + (size_t)i * 4) = o;
}

// C[M,N] = A[M,512] * W[N,512]^T + bias.  Tile 64x64, 4 waves, wave = 16 rows x 64 cols.
// Q output is pre-scaled by 1/sqrt(512).
__global__ __launch_bounds__(256) void gemm_qkv(
    const bf16* __restrict__ A,
    const bf16* __restrict__ Wqb, const bf16* __restrict__ Wkb, const bf16* __restrict__ Wvb,
    const float* __restrict__ bq, const float* __restrict__ bk, const float* __restrict__ bv,
    bf16* __restrict__ Qb, bf16* __restrict__ Kb, bf16* __restrict__ Vt) {
  int z = blockIdx.z;
  const bf16* W = (z == 0) ? Wqb : (z == 1) ? Wkb : Wvb;
  const float* bias = (z == 0) ? bq : (z == 1) ? bk : bv;
  int tid = threadIdx.x;
  int w = tid >> 6, l = tid & 63, lr = l & 15, lg = l >> 4;
  int row0 = blockIdx.x * 64 + w * 16;
  int col0 = blockIdx.y * 64;
  f32x4 acc[4] = {};
  const bf16* Ap = A + (size_t)(row0 + lr) * DMODEL + lg * 8;
  const bf16* Wp = W + (size_t)(col0 + lr) * DMODEL + lg * 8;
  for (int kk = 0; kk < 16; ++kk) {
    bf16x8 a = *(const bf16x8*)(Ap + kk * 32);
#pragma unroll
    for (int c = 0; c < 4; ++c) {
      bf16x8 bfr = *(const bf16x8*)(Wp + (size_t)c * 16 * DMODEL + kk * 32);
      acc[c] = __builtin_amdgcn_mfma_f32_16x16x32_bf16(a, bfr, acc[c], 0, 0, 0);
    }
  }
  if (z < 2) {
    bf16* O = (z == 0) ? Qb : Kb;
    float qs = (z == 0) ? INV_SQRT_D : 1.0f;
#pragma unroll
    for (int c = 0; c < 4; ++c) {
      int cg = col0 + 16 * c + lr;
      float bi = bias[cg];
#pragma unroll
      for (int r = 0; r < 4; ++r) {
        int rg = row0 + lg * 4 + r;
        O[(size_t)rg * DMODEL + cg] = (bf16)((acc[c][r] + bi) * qs);
      }
    }
  } else {
    // V: store transposed -> Vt[b][h][e][s]
    int h = blockIdx.y;            // col0 == h*64
    int b = row0 >> 11;
    int s0 = (row0 & 2047) + lg * 4;
#pragma unroll
    for (int c = 0; c < 4; ++c) {
      int e = 16 * c + lr;
      float bi = bias[col0 + e];
      bf16x4v pk;
#pragma unroll
      for (int r = 0; r < 4; ++r) pk[r] = (bf16)(acc[c][r] + bi);
      *(bf16x4v*)(Vt + ((size_t)((b * 8 + h) * 64 + e)) * S_LEN + s0) = pk;
    }
  }
}

// SUF[bh][j][e] = sum_{t >= 16j} V[t][e], j = 0..128 (SUF[128]=0).
// 256 threads: (e, seg) with 4 segments of 32 chunks; segmented suffix scan.
__global__ __launch_bounds__(256) void suf_kernel(const bf16* __restrict__ Vt,
                                                  float* __restrict__ SUF) {
  int bh = blockIdx.x;
  int e = threadIdx.x & 63;
  int seg = threadIdx.x >> 6;  // 0..3
  __shared__ float segtot[4][64];
  const bf16* vrow = Vt + ((size_t)bh * 64 + e) * S_LEN;
  float loc[32];
  float carry = 0.f;
#pragma unroll
  for (int j = 31; j >= 0; --j) {
    int jj = seg * 32 + j;
    bf16x8 a = *(const bf16x8*)(vrow + jj * 16);
    bf16x8 b2 = *(const bf16x8*)(vrow + jj * 16 + 8);
    float s = 0.f;
#pragma unroll
    for (int k = 0; k < 8; ++k) s += (float)a[k] + (float)b2[k];
    carry += s;
    loc[j] = carry;
  }
  segtot[seg][e] = carry;
  __syncthreads();
  float add = 0.f;
  for (int s2 = seg + 1; s2 < 4; ++s2) add += segtot[s2][e];
  float* srow = SUF + (size_t)bh * 129 * 64 + e;
#pragma unroll
  for (int j = 0; j < 32; ++j) srow[(size_t)(seg * 32 + j) * 64] = loc[j] + add;
  if (threadIdx.x < 64) srow[(size_t)128 * 64] = 0.f;
}

// Flash attention, flat softmax (no online max), KVBLK=64, XOR-swizzled LDS.
__global__ __launch_bounds__(256) void flash_attn(
    const bf16* __restrict__ Qb, const bf16* __restrict__ Kb,
    const bf16* __restrict__ Vt, const float* __restrict__ SUF,
    bf16* __restrict__ attO) {
  int bh = blockIdx.y;
  int b = bh >> 3, h = bh & 7;
  int qi = (int)gridDim.x - 1 - (int)blockIdx.x;  // largest-work blocks first
  int qb = qi * 64;
  int tid = threadIdx.x;
  int w = tid >> 6, l = tid & 63, lr = l & 15, lg = l >> 4;

  __shared__ __align__(16) bf16 kl[64 * 64];      // K tile [t][e], swizzled
  __shared__ __align__(16) bf16 vl[64 * 64];      // V^T tile [e][t], swizzled
  __shared__ __align__(16) bf16 pl[4][16 * 64];   // per-wave P tile [s][t], swizzled

  int srow = qb + 16 * w + lr;
  const bf16* qptr = Qb + ((size_t)(b * S_LEN) + srow) * DMODEL + h * 64 + lg * 8;
  bf16x8 aq0 = *(const bf16x8*)(qptr);
  bf16x8 aq1 = *(const bf16x8*)(qptr + 32);

  float lsum[4] = {0.f, 0.f, 0.f, 0.f};
  f32x4 acc[4] = {};

  int tmax_w = qb + 16 * w + 16;  // analytic tail starts here for this wave
  int tend = qb + 64;
  const bf16* Kbase = Kb + ((size_t)(b * S_LEN)) * DMODEL + h * 64;
  const bf16* Vbase = Vt + ((size_t)bh * 64) * S_LEN;

  // staging: thread -> (row 0..31 (+32), 16B chunk 0..7), swizzle chunk ^= row&7
  int grow = tid >> 3, gch = tid & 7;
  int so0 = grow * 128 + ((gch ^ (grow & 7)) << 4);
  int so1 = so0 + 32 * 128;  // (grow+32)&7 == grow&7

  // fragment-read byte offsets (chunk ^ (row&7)), rows differ by 16 -> same &7
  int sw0 = (lg ^ (lr & 7)) << 4;         // chunk lg
  int sw4 = sw0 ^ 0x40;                   // chunk lg+4
  char* klb = (char*)kl;
  char* vlb = (char*)vl;
  char* plb = (char*)pl[w];

  for (int t0 = 0; t0 < tend; t0 += 64) {
    const bf16* kg = Kbase + (size_t)(t0 + grow) * DMODEL + gch * 8;
    *(bf16x8*)(klb + so0) = *(const bf16x8*)kg;
    *(bf16x8*)(klb + so1) = *(const bf16x8*)(kg + 32 * DMODEL);
    const bf16* vg = Vbase + (size_t)grow * S_LEN + t0 + gch * 8;
    *(bf16x8*)(vlb + so0) = *(const bf16x8*)vg;
    *(bf16x8*)(vlb + so1) = *(const bf16x8*)(vg + 32 * S_LEN);
    __syncthreads();

    // QK^T: S[s][t], 4 column blocks x (k=64 over 2 chained MFMAs)
    f32x4 sfrag[4];
    const f32x4 fz = {0.f, 0.f, 0.f, 0.f};
#pragma unroll
    for (int c = 0; c < 4; ++c) {
      int rb = (16 * c + lr) * 128;
      bf16x8 bk0 = *(const bf16x8*)(klb + rb + sw0);
      bf16x8 bk1 = *(const bf16x8*)(klb + rb + sw4);
      f32x4 t = __builtin_amdgcn_mfma_f32_16x16x32_bf16(aq0, bk0, fz, 0, 0, 0);
      sfrag[c] = __builtin_amdgcn_mfma_f32_16x16x32_bf16(aq1, bk1, t, 0, 0, 0);
    }

    // flat softmax: p = exp(x); masked in-region -> x=0; beyond tmax_w -> p=0
#pragma unroll
    for (int r = 0; r < 4; ++r) {
      int sg = qb + 16 * w + lg * 4 + r;
      int row = lg * 4 + r;
      int pbase = row * 128 + ((lr & 7) << 1);
      int xorv = row & 7;
      float psum = 0.f;
#pragma unroll
      for (int c = 0; c < 4; ++c) {
        int tg = t0 + 16 * c + lr;
        float x = (tg <= sg) ? sfrag[c][r] : ((tg < tmax_w) ? 0.f : -1e30f);
        float p = __expf(x);
        psum += p;
        int chunk = 2 * c + (lr >> 3);
        *(bf16*)(plb + pbase + (((chunk ^ xorv) << 4))) = (bf16)p;
      }
      lsum[r] += psum;
    }

    // PV: A = P (from per-wave LDS), B = V^T tile
    bf16x8 pa0 = *(const bf16x8*)(plb + lr * 128 + sw0);
    bf16x8 pa1 = *(const bf16x8*)(plb + lr * 128 + sw4);
#pragma unroll
    for (int c = 0; c < 4; ++c) {
      int rb = (16 * c + lr) * 128;
      bf16x8 bv0 = *(const bf16x8*)(vlb + rb + sw0);
      bf16x8 bv1 = *(const bf16x8*)(vlb + rb + sw4);
      acc[c] = __builtin_amdgcn_mfma_f32_16x16x32_bf16(pa0, bv0, acc[c], 0, 0, 0);
      acc[c] = __builtin_amdgcn_mfma_f32_16x16x32_bf16(pa1, bv1, acc[c], 0, 0, 0);
    }
    __syncthreads();
  }

  // single end-of-kernel reduction of lsum across the 16 t-lanes
#pragma unroll
  for (int r = 0; r < 4; ++r) {
#pragma unroll
    for (int d = 1; d < 16; d <<= 1) lsum[r] += __shfl_xor(lsum[r], d, 64);
  }

  int j16 = tmax_w >> 4;
  const float* suf = SUF + ((size_t)bh * 129 + j16) * 64;
  float cnt = (float)(S_LEN - tmax_w);
  float sufe[4];
#pragma unroll
  for (int c = 0; c < 4; ++c) sufe[c] = suf[16 * c + lr];
#pragma unroll
  for (int r = 0; r < 4; ++r) {
    float inv = 1.f / (lsum[r] + cnt);
    int sg = qb + 16 * w + lg * 4 + r;
#pragma unroll
    for (int c = 0; c < 4; ++c) {
      float o = (acc[c][r] + sufe[c]) * inv;
      attO[((size_t)(b * S_LEN) + sg) * DMODEL + h * 64 + 16 * c + lr] = (bf16)o;
    }
  }
}

__global__ __launch_bounds__(256) void gemm_wo(
    const bf16* __restrict__ A, const bf16* __restrict__ W,
    const float* __restrict__ bo, const float* __restrict__ embed,
    float* __restrict__ X) {
  int tid = threadIdx.x;
  int w = tid >> 6, l = tid & 63, lr = l & 15, lg = l >> 4;
  int row0 = blockIdx.x * 64 + w * 16;
  int col0 = blockIdx.y * 64;
  f32x4 acc[4] = {};
  const bf16* Ap = A + (size_t)(row0 + lr) * DMODEL + lg * 8;
  const bf16* Wp = W + (size_t)(col0 + lr) * DMODEL + lg * 8;
  for (int kk = 0; kk < 16; ++kk) {
    bf16x8 a = *(const bf16x8*)(Ap + kk * 32);
#pragma unroll
    for (int c = 0; c < 4; ++c) {
      bf16x8 bfr = *(const bf16x8*)(Wp + (size_t)c * 16 * DMODEL + kk * 32);
      acc[c] = __builtin_amdgcn_mfma_f32_16x16x32_bf16(a, bfr, acc[c], 0, 0, 0);
    }
  }
#pragma unroll
  for (int c = 0; c < 4; ++c) {
    int cg = col0 + 16 * c + lr;
    float bi = bo[cg];
#pragma unroll
    for (int r = 0; r < 4; ++r) {
      int rg = row0 + lg * 4 + r;
      X[(size_t)rg * DMODEL + cg] = acc[c][r] + bi + embed[(size_t)rg * DMODEL + cg];
    }
  }
}

__global__ __launch_bounds__(256) void ln_kernel(const float* __restrict__ x,
                                                 const float* __restrict__ gamma,
                                                 const float* __restrict__ beta,
                                                 float* __restrict__ out) {
  int row = blockIdx.x * 4 + (threadIdx.x >> 6);
  int l = threadIdx.x & 63;
  const float4* xr = reinterpret_cast<const float4*>(x + (size_t)row * DMODEL) + l * 2;
  float4 v0 = xr[0], v1 = xr[1];
  float s = v0.x + v0.y + v0.z + v0.w + v1.x + v1.y + v1.z + v1.w;
  float s2 = v0.x * v0.x + v0.y * v0.y + v0.z * v0.z + v0.w * v0.w +
             v1.x * v1.x + v1.y * v1.y + v1.z * v1.z + v1.w * v1.w;
#pragma unroll
  for (int d = 1; d < 64; d <<= 1) {
    s += __shfl_xor(s, d, 64);
    s2 += __shfl_xor(s2, d, 64);
  }
  float mean = s * (1.f / 512.f);
  float var = s2 * (1.f / 512.f) - mean * mean;
  float rstd = rsqrtf(var + 1e-5f);
  const float4* g4 = reinterpret_cast<const float4*>(gamma) + l * 2;
  const float4* b4 = reinterpret_cast<const float4*>(beta) + l * 2;
  float4 g0 = g4[0], g1 = g4[1], bb0 = b4[0], bb1 = b4[1];
  float4 o0, o1;
  o0.x = (v0.x - mean) * rstd * g0.x + bb0.x;
  o0.y = (v0.y - mean) * rstd * g0.y + bb0.y;
  o0.z = (v0.z - mean) * rstd * g0.z + bb0.z;
  o0.w = (v0.w - mean) * rstd * g0.w + bb0.w;
  o1.x = (v1.x - mean) * rstd * g1.x + bb1.x;
  o1.y = (v1.y - mean) * rstd * g1.y + bb1.y;
  o1.z = (v1.z - mean) * rstd * g1.z + bb1.z;
  o1.w = (v1.w - mean) * rstd * g1.w + bb1.w;
  float4* orow = reinterpret_cast<float4*>(out + (size_t)row * DMODEL) + l * 2;
  orow[0] = o0;
  orow[1] = o1;
}

extern "C" void kernel_launch(void* const* d_in, const int* in_sizes, int n_in,
                              void* d_out, int out_size, void* d_ws, size_t ws_size,
                              hipStream_t stream) {
  const float* embed = (const float*)d_in[0];
  const float* Wq = (const float*)d_in[1];
  const float* bq = (const float*)d_in[2];
  const float* Wk = (const float*)d_in[3];
  const float* bk = (const float*)d_in[4];
  const float* Wv = (const float*)d_in[5];
  const float* bv = (const float*)d_in[6];
  const float* Wo = (const float*)d_in[7];
  const float* bo = (const float*)d_in[8];
  const float* gamma = (const float*)d_in[9];
  const float* beta = (const float*)d_in[10];
  float* out = (float*)d_out;

  char* ws = (char*)d_ws;
  size_t off = 0;
  auto alc = [&](size_t b) { size_t o = off; off += (b + 255) & ~(size_t)255; return o; };
  bf16* Eb   = (bf16*)(ws + alc(8192ull * 512 * 2));
  bf16* Wqb  = (bf16*)(ws + alc(512ull * 512 * 2));
  bf16* Wkb  = (bf16*)(ws + alc(512ull * 512 * 2));
  bf16* Wvb  = (bf16*)(ws + alc(512ull * 512 * 2));
  bf16* Wob  = (bf16*)(ws + alc(512ull * 512 * 2));
  bf16* Qb   = (bf16*)(ws + alc(8192ull * 512 * 2));
  bf16* Kb   = (bf16*)(ws + alc(8192ull * 512 * 2));
  bf16* Vt   = (bf16*)(ws + alc(8192ull * 512 * 2));
  float* SUF = (float*)(ws + alc(32ull * 129 * 64 * 4));
  bf16* AttO = (bf16*)(ws + alc(8192ull * 512 * 2));
  float* Xb  = (float*)(ws + alc(8192ull * 512 * 4));
  (void)ws_size; (void)n_in; (void)in_sizes; (void)out_size;

  cast_f32_bf16<<<4096, 256, 0, stream>>>(embed, Eb, 4194304 / 4);
  cast4_f32_bf16<<<dim3(256, 4), 256, 0, stream>>>(Wq, Wk, Wv, Wo, Wqb, Wkb, Wvb, Wob);

  gemm_qkv<<<dim3(128, 8, 3), 256, 0, stream>>>(Eb, Wqb, Wkb, Wvb, bq, bk, bv, Qb, Kb, Vt);
  suf_kernel<<<32, 256, 0, stream>>>(Vt, SUF);
  flash_attn<<<dim3(32, 32), 256, 0, stream>>>(Qb, Kb, Vt, SUF, AttO);
  gemm_wo<<<dim3(128, 8), 256, 0, stream>>>(AttO, Wob, bo, embed, Xb);
  ln_kernel<<<2048, 256, 0, stream>>>(Xb, gamma, beta, out);
}

// Round 4
// 133.274 us; speedup vs baseline: 2.7370x; 1.8274x over previous
//
#include <hip/hip_runtime.h>
#include <hip/hip_bf16.h>

// B=4, S=2048, D=512, H=8, DH=64
// m97-structure 128x128 LDS-staged GEMMs (global_load_lds w16 + XOR swizzle),
// flat-softmax flash attention (scores analytically bounded; tril zeros pin max~0),
// masked tail folded analytically via V suffix sums.

typedef __bf16 bf16;
typedef __bf16 bf16x8 __attribute__((ext_vector_type(8)));
typedef __bf16 bf16x4v __attribute__((ext_vector_type(4)));
typedef float f32x4 __attribute__((ext_vector_type(4)));

#define S_LEN 2048
#define DMODEL 512
#define INV_SQRT_D 0.044194173824159216f  // 1/sqrt(512)

#define GLDS(g, l) __builtin_amdgcn_global_load_lds(                  \
    (const __attribute__((address_space(1))) void*)(g),               \
    (__attribute__((address_space(3))) void*)(l), 16, 0, 0)

__global__ __launch_bounds__(256) void cast_f32_bf16(const float* __restrict__ in,
                                                     bf16* __restrict__ out, int n4) {
  int i = blockIdx.x * blockDim.x + threadIdx.x;
  if (i < n4) {
    float4 v = reinterpret_cast<const float4*>(in)[i];
    bf16x4v o;
    o[0] = (bf16)v.x; o[1] = (bf16)v.y; o[2] = (bf16)v.z; o[3] = (bf16)v.w;
    *reinterpret_cast<bf16x4v*>(out + (size_t)i * 4) = o;
  }
}

// Wq,Wk,Wv -> contiguous Wqkv[1536][512]; Wo -> Wob
__global__ __launch_bounds__(256) void cast4_f32_bf16(
    const float* __restrict__ a0, const float* __restrict__ a1,
    const float* __restrict__ a2, const float* __restrict__ a3,
    bf16* __restrict__ o0, bf16* __restrict__ o1,
    bf16* __restrict__ o2, bf16* __restrict__ o3) {
  int y = blockIdx.y;
  const float* in = (y == 0) ? a0 : (y == 1) ? a1 : (y == 2) ? a2 : a3;
  bf16* out = (y == 0) ? o0 : (y == 1) ? o1 : (y == 2) ? o2 : o3;
  int i = blockIdx.x * blockDim.x + threadIdx.x;
  float4 v = reinterpret_cast<const float4*>(in)[i];
  bf16x4v o;
  o[0] = (bf16)v.x; o[1] = (bf16)v.y; o[2] = (bf16)v.z; o[3] = (bf16)v.w;
  *reinterpret_cast<bf16x4v*>(out + (size_t)i * 4) = o;
}

// ---- 128x128 tile GEMM core: C = A[M,512] * Bw[N,512]^T, K=512, BK=64 ----
// 4 waves (2x2), per-wave 4x4 fragments of 16x16x32 MFMA.
// LDS linear dest via global_load_lds; source pre-swizzled chunk^=(row&7); reads
// apply the same XOR -> conflict-free ds_read_b128.
__device__ __forceinline__ void gemm128_core(
    const bf16* __restrict__ A, const bf16* __restrict__ Bw,
    int row0, int col0, bf16* As, bf16* Bs, f32x4 (&acc)[4][4]) {
  int tid = threadIdx.x;
  int w = tid >> 6, l = tid & 63, lr = l & 15, lg = l >> 4;
  int wr = w >> 1, wc = w & 1;

  int srow = w * 8 + (l >> 3);            // 0..31 (row within 32-row quarter)
  int scol = ((l & 7) ^ (srow & 7)) << 3; // pre-swizzled k-chunk
  const bf16* ga = A + (size_t)(row0 + srow) * DMODEL + scol;
  const bf16* gb = Bw + (size_t)(col0 + srow) * DMODEL + scol;
  char* asb = (char*)As;
  char* bsb = (char*)Bs;
  int sbase = w * 1024;                   // + qt*4096, lane offset implicit

  // fragment read offsets: row*128 + ((lg ^ (lr&7))<<4); kh=1 -> ^0x40
  int aoff[4], boff[4];
#pragma unroll
  for (int m = 0; m < 4; ++m) {
    aoff[m] = (wr * 64 + m * 16 + lr) * 128 + (((lg ^ (lr & 7))) << 4);
    boff[m] = (wc * 64 + m * 16 + lr) * 128 + (((lg ^ (lr & 7))) << 4);
  }

  for (int k0 = 0; k0 < DMODEL; k0 += 64) {
#pragma unroll
    for (int qt = 0; qt < 4; ++qt) {
      GLDS(ga + (size_t)qt * 32 * DMODEL, asb + qt * 4096 + sbase);
      GLDS(gb + (size_t)qt * 32 * DMODEL, bsb + qt * 4096 + sbase);
    }
    ga += 64; gb += 64;
    __syncthreads();

    bf16x8 af[2][4], bfv[2][4];
#pragma unroll
    for (int m = 0; m < 4; ++m) {
      af[0][m] = *(const bf16x8*)(asb + aoff[m]);
      af[1][m] = *(const bf16x8*)(asb + (aoff[m] ^ 0x40));
      bfv[0][m] = *(const bf16x8*)(bsb + boff[m]);
      bfv[1][m] = *(const bf16x8*)(bsb + (boff[m] ^ 0x40));
    }
#pragma unroll
    for (int m = 0; m < 4; ++m)
#pragma unroll
      for (int n = 0; n < 4; ++n) {
        acc[m][n] = __builtin_amdgcn_mfma_f32_16x16x32_bf16(af[0][m], bfv[0][n], acc[m][n], 0, 0, 0);
        acc[m][n] = __builtin_amdgcn_mfma_f32_16x16x32_bf16(af[1][m], bfv[1][n], acc[m][n], 0, 0, 0);
      }
    __syncthreads();
  }
}

// Fused QKV GEMM: Wqkv[1536][512]; blockIdx.y 0-3 = Q, 4-7 = K, 8-11 = V.
__global__ __launch_bounds__(256) void gemm_qkv(
    const bf16* __restrict__ A, const bf16* __restrict__ Wqkv,
    const float* __restrict__ bq, const float* __restrict__ bk, const float* __restrict__ bv,
    bf16* __restrict__ Qb, bf16* __restrict__ Kb, bf16* __restrict__ Vt) {
  __shared__ __align__(16) bf16 As[128 * 64];
  __shared__ __align__(16) bf16 Bs[128 * 64];
  int row0 = blockIdx.x * 128, col0 = blockIdx.y * 128;
  f32x4 acc[4][4] = {};
  gemm128_core(A, Wqkv, row0, col0, As, Bs, acc);

  int tid = threadIdx.x;
  int w = tid >> 6, l = tid & 63, lr = l & 15, lg = l >> 4;
  int wr = w >> 1, wc = w & 1;
  int z2 = col0 >> 9;  // 0=Q 1=K 2=V (uniform per block)
  if (z2 < 2) {
    bf16* O = z2 ? Kb : Qb;
    const float* bias = z2 ? bk : bq;
    float qs = z2 ? 1.0f : INV_SQRT_D;
#pragma unroll
    for (int n = 0; n < 4; ++n) {
      int cg = (col0 & 511) + wc * 64 + n * 16 + lr;
      float bi = bias[cg];
#pragma unroll
      for (int m = 0; m < 4; ++m) {
        int rg = row0 + wr * 64 + m * 16 + lg * 4;
#pragma unroll
        for (int r = 0; r < 4; ++r)
          O[(size_t)(rg + r) * DMODEL + cg] = (bf16)((acc[m][n][r] + bi) * qs);
      }
    }
  } else {
    // V: store transposed Vt[b][h][e][s]
#pragma unroll
    for (int n = 0; n < 4; ++n) {
      int ep = (col0 & 511) + wc * 64 + n * 16 + lr;  // 0..511
      int h = ep >> 6, e = ep & 63;
      float bi = bv[ep];
#pragma unroll
      for (int m = 0; m < 4; ++m) {
        int rg = row0 + wr * 64 + m * 16 + lg * 4;
        int b = rg >> 11, s0 = rg & 2047;
        bf16x4v pk;
#pragma unroll
        for (int r = 0; r < 4; ++r) pk[r] = (bf16)(acc[m][n][r] + bi);
        *(bf16x4v*)(Vt + ((size_t)((b * 8 + h) * 64 + e)) * S_LEN + s0) = pk;
      }
    }
  }
}

// Wo GEMM + bias + residual, f32 out.
__global__ __launch_bounds__(256) void gemm_wo(
    const bf16* __restrict__ A, const bf16* __restrict__ W,
    const float* __restrict__ bo, const float* __restrict__ embed,
    float* __restrict__ X) {
  __shared__ __align__(16) bf16 As[128 * 64];
  __shared__ __align__(16) bf16 Bs[128 * 64];
  int row0 = blockIdx.x * 128, col0 = blockIdx.y * 128;
  f32x4 acc[4][4] = {};
  gemm128_core(A, W, row0, col0, As, Bs, acc);

  int tid = threadIdx.x;
  int w = tid >> 6, l = tid & 63, lr = l & 15, lg = l >> 4;
  int wr = w >> 1, wc = w & 1;
#pragma unroll
  for (int n = 0; n < 4; ++n) {
    int cg = col0 + wc * 64 + n * 16 + lr;
    float bi = bo[cg];
#pragma unroll
    for (int m = 0; m < 4; ++m) {
      int rg = row0 + wr * 64 + m * 16 + lg * 4;
#pragma unroll
      for (int r = 0; r < 4; ++r)
        X[(size_t)(rg + r) * DMODEL + cg] =
            acc[m][n][r] + bi + embed[(size_t)(rg + r) * DMODEL + cg];
    }
  }
}

// SUF[bh][j][e] = sum_{t >= 16j} V[t][e], j = 0..128 (SUF[128]=0).
__global__ __launch_bounds__(256) void suf_kernel(const bf16* __restrict__ Vt,
                                                  float* __restrict__ SUF) {
  int bh = blockIdx.x;
  int e = threadIdx.x & 63;
  int seg = threadIdx.x >> 6;  // 0..3
  __shared__ float segtot[4][64];
  const bf16* vrow = Vt + ((size_t)bh * 64 + e) * S_LEN;
  float loc[32];
  float carry = 0.f;
#pragma unroll
  for (int j = 31; j >= 0; --j) {
    int jj = seg * 32 + j;
    bf16x8 a = *(const bf16x8*)(vrow + jj * 16);
    bf16x8 b2 = *(const bf16x8*)(vrow + jj * 16 + 8);
    float s = 0.f;
#pragma unroll
    for (int k = 0; k < 8; ++k) s += (float)a[k] + (float)b2[k];
    carry += s;
    loc[j] = carry;
  }
  segtot[seg][e] = carry;
  __syncthreads();
  float add = 0.f;
  for (int s2 = seg + 1; s2 < 4; ++s2) add += segtot[s2][e];
  float* srow = SUF + (size_t)bh * 129 * 64 + e;
#pragma unroll
  for (int j = 0; j < 32; ++j) srow[(size_t)(seg * 32 + j) * 64] = loc[j] + add;
  if (threadIdx.x < 64) srow[(size_t)128 * 64] = 0.f;
}

// Flash attention, flat softmax (no online max), KVBLK=64, XOR-swizzled LDS.
__global__ __launch_bounds__(256) void flash_attn(
    const bf16* __restrict__ Qb, const bf16* __restrict__ Kb,
    const bf16* __restrict__ Vt, const float* __restrict__ SUF,
    bf16* __restrict__ attO) {
  int bh = blockIdx.y;
  int b = bh >> 3, h = bh & 7;
  int qi = (int)gridDim.x - 1 - (int)blockIdx.x;  // largest-work blocks first
  int qb = qi * 64;
  int tid = threadIdx.x;
  int w = tid >> 6, l = tid & 63, lr = l & 15, lg = l >> 4;

  __shared__ __align__(16) bf16 kl[64 * 64];
  __shared__ __align__(16) bf16 vl[64 * 64];
  __shared__ __align__(16) bf16 pl[4][16 * 64];

  int srow = qb + 16 * w + lr;
  const bf16* qptr = Qb + ((size_t)(b * S_LEN) + srow) * DMODEL + h * 64 + lg * 8;
  bf16x8 aq0 = *(const bf16x8*)(qptr);
  bf16x8 aq1 = *(const bf16x8*)(qptr + 32);

  float lsum[4] = {0.f, 0.f, 0.f, 0.f};
  f32x4 acc[4] = {};

  int tmax_w = qb + 16 * w + 16;
  int tend = qb + 64;
  const bf16* Kbase = Kb + ((size_t)(b * S_LEN)) * DMODEL + h * 64;
  const bf16* Vbase = Vt + ((size_t)bh * 64) * S_LEN;

  int grow = tid >> 3, gch = tid & 7;
  int so0 = grow * 128 + ((gch ^ (grow & 7)) << 4);
  int so1 = so0 + 32 * 128;

  int sw0 = (lg ^ (lr & 7)) << 4;
  int sw4 = sw0 ^ 0x40;
  char* klb = (char*)kl;
  char* vlb = (char*)vl;
  char* plb = (char*)pl[w];

  for (int t0 = 0; t0 < tend; t0 += 64) {
    const bf16* kg = Kbase + (size_t)(t0 + grow) * DMODEL + gch * 8;
    *(bf16x8*)(klb + so0) = *(const bf16x8*)kg;
    *(bf16x8*)(klb + so1) = *(const bf16x8*)(kg + 32 * DMODEL);
    const bf16* vg = Vbase + (size_t)grow * S_LEN + t0 + gch * 8;
    *(bf16x8*)(vlb + so0) = *(const bf16x8*)vg;
    *(bf16x8*)(vlb + so1) = *(const bf16x8*)(vg + 32 * S_LEN);
    __syncthreads();

    f32x4 sfrag[4];
    const f32x4 fz = {0.f, 0.f, 0.f, 0.f};
#pragma unroll
    for (int c = 0; c < 4; ++c) {
      int rb = (16 * c + lr) * 128;
      bf16x8 bk0 = *(const bf16x8*)(klb + rb + sw0);
      bf16x8 bk1 = *(const bf16x8*)(klb + rb + sw4);
      f32x4 t = __builtin_amdgcn_mfma_f32_16x16x32_bf16(aq0, bk0, fz, 0, 0, 0);
      sfrag[c] = __builtin_amdgcn_mfma_f32_16x16x32_bf16(aq1, bk1, t, 0, 0, 0);
    }

#pragma unroll
    for (int r = 0; r < 4; ++r) {
      int sg = qb + 16 * w + lg * 4 + r;
      int row = lg * 4 + r;
      int pbase = row * 128 + ((lr & 7) << 1);
      int xorv = row & 7;
      float psum = 0.f;
#pragma unroll
      for (int c = 0; c < 4; ++c) {
        int tg = t0 + 16 * c + lr;
        float x = (tg <= sg) ? sfrag[c][r] : ((tg < tmax_w) ? 0.f : -1e30f);
        float p = __expf(x);
        psum += p;
        int chunk = 2 * c + (lr >> 3);
        *(bf16*)(plb + pbase + (((chunk ^ xorv) << 4))) = (bf16)p;
      }
      lsum[r] += psum;
    }

    bf16x8 pa0 = *(const bf16x8*)(plb + lr * 128 + sw0);
    bf16x8 pa1 = *(const bf16x8*)(plb + lr * 128 + sw4);
#pragma unroll
    for (int c = 0; c < 4; ++c) {
      int rb = (16 * c + lr) * 128;
      bf16x8 bv0 = *(const bf16x8*)(vlb + rb + sw0);
      bf16x8 bv1 = *(const bf16x8*)(vlb + rb + sw4);
      acc[c] = __builtin_amdgcn_mfma_f32_16x16x32_bf16(pa0, bv0, acc[c], 0, 0, 0);
      acc[c] = __builtin_amdgcn_mfma_f32_16x16x32_bf16(pa1, bv1, acc[c], 0, 0, 0);
    }
    __syncthreads();
  }

#pragma unroll
  for (int r = 0; r < 4; ++r) {
#pragma unroll
    for (int d = 1; d < 16; d <<= 1) lsum[r] += __shfl_xor(lsum[r], d, 64);
  }

  int j16 = tmax_w >> 4;
  const float* suf = SUF + ((size_t)bh * 129 + j16) * 64;
  float cnt = (float)(S_LEN - tmax_w);
  float sufe[4];
#pragma unroll
  for (int c = 0; c < 4; ++c) sufe[c] = suf[16 * c + lr];
#pragma unroll
  for (int r = 0; r < 4; ++r) {
    float inv = 1.f / (lsum[r] + cnt);
    int sg = qb + 16 * w + lg * 4 + r;
#pragma unroll
    for (int c = 0; c < 4; ++c) {
      float o = (acc[c][r] + sufe[c]) * inv;
      attO[((size_t)(b * S_LEN) + sg) * DMODEL + h * 64 + 16 * c + lr] = (bf16)o;
    }
  }
}

__global__ __launch_bounds__(256) void ln_kernel(const float* __restrict__ x,
                                                 const float* __restrict__ gamma,
                                                 const float* __restrict__ beta,
                                                 float* __restrict__ out) {
  int row = blockIdx.x * 4 + (threadIdx.x >> 6);
  int l = threadIdx.x & 63;
  const float4* xr = reinterpret_cast<const float4*>(x + (size_t)row * DMODEL) + l * 2;
  float4 v0 = xr[0], v1 = xr[1];
  float s = v0.x + v0.y + v0.z + v0.w + v1.x + v1.y + v1.z + v1.w;
  float s2 = v0.x * v0.x + v0.y * v0.y + v0.z * v0.z + v0.w * v0.w +
             v1.x * v1.x + v1.y * v1.y + v1.z * v1.z + v1.w * v1.w;
#pragma unroll
  for (int d = 1; d < 64; d <<= 1) {
    s += __shfl_xor(s, d, 64);
    s2 += __shfl_xor(s2, d, 64);
  }
  float mean = s * (1.f / 512.f);
  float var = s2 * (1.f / 512.f) - mean * mean;
  float rstd = rsqrtf(var + 1e-5f);
  const float4* g4 = reinterpret_cast<const float4*>(gamma) + l * 2;
  const float4* b4 = reinterpret_cast<const float4*>(beta) + l * 2;
  float4 g0 = g4[0], g1 = g4[1], bb0 = b4[0], bb1 = b4[1];
  float4 o0, o1;
  o0.x = (v0.x - mean) * rstd * g0.x + bb0.x;
  o0.y = (v0.y - mean) * rstd * g0.y + bb0.y;
  o0.z = (v0.z - mean) * rstd * g0.z + bb0.z;
  o0.w = (v0.w - mean) * rstd * g0.w + bb0.w;
  o1.x = (v1.x - mean) * rstd * g1.x + bb1.x;
  o1.y = (v1.y - mean) * rstd * g1.y + bb1.y;
  o1.z = (v1.z - mean) * rstd * g1.z + bb1.z;
  o1.w = (v1.w - mean) * rstd * g1.w + bb1.w;
  float4* orow = reinterpret_cast<float4*>(out + (size_t)row * DMODEL) + l * 2;
  orow[0] = o0;
  orow[1] = o1;
}

extern "C" void kernel_launch(void* const* d_in, const int* in_sizes, int n_in,
                              void* d_out, int out_size, void* d_ws, size_t ws_size,
                              hipStream_t stream) {
  const float* embed = (const float*)d_in[0];
  const float* Wq = (const float*)d_in[1];
  const float* bq = (const float*)d_in[2];
  const float* Wk = (const float*)d_in[3];
  const float* bk = (const float*)d_in[4];
  const float* Wv = (const float*)d_in[5];
  const float* bv = (const float*)d_in[6];
  const float* Wo = (const float*)d_in[7];
  const float* bo = (const float*)d_in[8];
  const float* gamma = (const float*)d_in[9];
  const float* beta = (const float*)d_in[10];
  float* out = (float*)d_out;

  char* ws = (char*)d_ws;
  size_t off = 0;
  auto alc = [&](size_t b) { size_t o = off; off += (b + 255) & ~(size_t)255; return o; };
  bf16* Eb    = (bf16*)(ws + alc(8192ull * 512 * 2));
  bf16* Wqkv  = (bf16*)(ws + alc(1536ull * 512 * 2));
  bf16* Wob   = (bf16*)(ws + alc(512ull * 512 * 2));
  bf16* Qb    = (bf16*)(ws + alc(8192ull * 512 * 2));
  bf16* Kb    = (bf16*)(ws + alc(8192ull * 512 * 2));
  bf16* Vt    = (bf16*)(ws + alc(8192ull * 512 * 2));
  float* SUF  = (float*)(ws + alc(32ull * 129 * 64 * 4));
  bf16* AttO  = (bf16*)(ws + alc(8192ull * 512 * 2));
  float* Xb   = (float*)(ws + alc(8192ull * 512 * 4));
  (void)ws_size; (void)n_in; (void)in_sizes; (void)out_size;

  cast_f32_bf16<<<4096, 256, 0, stream>>>(embed, Eb, 4194304 / 4);
  cast4_f32_bf16<<<dim3(256, 4), 256, 0, stream>>>(
      Wq, Wk, Wv, Wo, Wqkv, Wqkv + 512ull * 512, Wqkv + 1024ull * 512, Wob);

  gemm_qkv<<<dim3(64, 12), 256, 0, stream>>>(Eb, Wqkv, bq, bk, bv, Qb, Kb, Vt);
  suf_kernel<<<32, 256, 0, stream>>>(Vt, SUF);
  flash_attn<<<dim3(32, 32), 256, 0, stream>>>(Qb, Kb, Vt, SUF, AttO);
  gemm_wo<<<dim3(64, 4), 256, 0, stream>>>(AttO, Wob, bo, embed, Xb);
  ln_kernel<<<2048, 256, 0, stream>>>(Xb, gamma, beta, out);
}

// Round 5
// 130.191 us; speedup vs baseline: 2.8018x; 1.0237x over previous
//
#include <hip/hip_runtime.h>
#include <hip/hip_bf16.h>

// B=4, S=2048, D=512, H=8, DH=64
// m97-structure 128x128 LDS-staged GEMMs (global_load_lds w16 + XOR swizzle),
// flat-softmax flash attention (scores analytically bounded; tril zeros pin max~0),
// masked tail folded analytically via V suffix sums.
// flash v2: 8 waves x 16 q-rows (QBLK=128), double-buffered GLDS 2-phase pipeline,
// one barrier per KV tile, wave-uniform compute skip + interior fast path.

typedef __bf16 bf16;
typedef __bf16 bf16x8 __attribute__((ext_vector_type(8)));
typedef __bf16 bf16x4v __attribute__((ext_vector_type(4)));
typedef float f32x4 __attribute__((ext_vector_type(4)));

#define S_LEN 2048
#define DMODEL 512
#define INV_SQRT_D 0.044194173824159216f  // 1/sqrt(512)

#define GLDS(g, l) __builtin_amdgcn_global_load_lds(                  \
    (const __attribute__((address_space(1))) void*)(g),               \
    (__attribute__((address_space(3))) void*)(l), 16, 0, 0)

__global__ __launch_bounds__(256) void cast_f32_bf16(const float* __restrict__ in,
                                                     bf16* __restrict__ out, int n4) {
  int i = blockIdx.x * blockDim.x + threadIdx.x;
  if (i < n4) {
    float4 v = reinterpret_cast<const float4*>(in)[i];
    bf16x4v o;
    o[0] = (bf16)v.x; o[1] = (bf16)v.y; o[2] = (bf16)v.z; o[3] = (bf16)v.w;
    *reinterpret_cast<bf16x4v*>(out + (size_t)i * 4) = o;
  }
}

// Wq,Wk,Wv -> contiguous Wqkv[1536][512]; Wo -> Wob
__global__ __launch_bounds__(256) void cast4_f32_bf16(
    const float* __restrict__ a0, const float* __restrict__ a1,
    const float* __restrict__ a2, const float* __restrict__ a3,
    bf16* __restrict__ o0, bf16* __restrict__ o1,
    bf16* __restrict__ o2, bf16* __restrict__ o3) {
  int y = blockIdx.y;
  const float* in = (y == 0) ? a0 : (y == 1) ? a1 : (y == 2) ? a2 : a3;
  bf16* out = (y == 0) ? o0 : (y == 1) ? o1 : (y == 2) ? o2 : o3;
  int i = blockIdx.x * blockDim.x + threadIdx.x;
  float4 v = reinterpret_cast<const float4*>(in)[i];
  bf16x4v o;
  o[0] = (bf16)v.x; o[1] = (bf16)v.y; o[2] = (bf16)v.z; o[3] = (bf16)v.w;
  *reinterpret_cast<bf16x4v*>(out + (size_t)i * 4) = o;
}

// ---- 128x128 tile GEMM core: C = A[M,512] * Bw[N,512]^T, K=512, BK=64 ----
__device__ __forceinline__ void gemm128_core(
    const bf16* __restrict__ A, const bf16* __restrict__ Bw,
    int row0, int col0, bf16* As, bf16* Bs, f32x4 (&acc)[4][4]) {
  int tid = threadIdx.x;
  int w = tid >> 6, l = tid & 63, lr = l & 15, lg = l >> 4;
  int wr = w >> 1, wc = w & 1;

  int srow = w * 8 + (l >> 3);
  int scol = ((l & 7) ^ (srow & 7)) << 3;
  const bf16* ga = A + (size_t)(row0 + srow) * DMODEL + scol;
  const bf16* gb = Bw + (size_t)(col0 + srow) * DMODEL + scol;
  char* asb = (char*)As;
  char* bsb = (char*)Bs;
  int sbase = w * 1024;

  int aoff[4], boff[4];
#pragma unroll
  for (int m = 0; m < 4; ++m) {
    aoff[m] = (wr * 64 + m * 16 + lr) * 128 + (((lg ^ (lr & 7))) << 4);
    boff[m] = (wc * 64 + m * 16 + lr) * 128 + (((lg ^ (lr & 7))) << 4);
  }

  for (int k0 = 0; k0 < DMODEL; k0 += 64) {
#pragma unroll
    for (int qt = 0; qt < 4; ++qt) {
      GLDS(ga + (size_t)qt * 32 * DMODEL, asb + qt * 4096 + sbase);
      GLDS(gb + (size_t)qt * 32 * DMODEL, bsb + qt * 4096 + sbase);
    }
    ga += 64; gb += 64;
    __syncthreads();

    bf16x8 af[2][4], bfv[2][4];
#pragma unroll
    for (int m = 0; m < 4; ++m) {
      af[0][m] = *(const bf16x8*)(asb + aoff[m]);
      af[1][m] = *(const bf16x8*)(asb + (aoff[m] ^ 0x40));
      bfv[0][m] = *(const bf16x8*)(bsb + boff[m]);
      bfv[1][m] = *(const bf16x8*)(bsb + (boff[m] ^ 0x40));
    }
#pragma unroll
    for (int m = 0; m < 4; ++m)
#pragma unroll
      for (int n = 0; n < 4; ++n) {
        acc[m][n] = __builtin_amdgcn_mfma_f32_16x16x32_bf16(af[0][m], bfv[0][n], acc[m][n], 0, 0, 0);
        acc[m][n] = __builtin_amdgcn_mfma_f32_16x16x32_bf16(af[1][m], bfv[1][n], acc[m][n], 0, 0, 0);
      }
    __syncthreads();
  }
}

// Fused QKV GEMM: Wqkv[1536][512]; col-tiles 0-3 = Q, 4-7 = K, 8-11 = V.
__global__ __launch_bounds__(256) void gemm_qkv(
    const bf16* __restrict__ A, const bf16* __restrict__ Wqkv,
    const float* __restrict__ bq, const float* __restrict__ bk, const float* __restrict__ bv,
    bf16* __restrict__ Qb, bf16* __restrict__ Kb, bf16* __restrict__ Vt) {
  __shared__ __align__(16) bf16 As[128 * 64];
  __shared__ __align__(16) bf16 Bs[128 * 64];
  int row0 = blockIdx.x * 128, col0 = blockIdx.y * 128;
  f32x4 acc[4][4] = {};
  gemm128_core(A, Wqkv, row0, col0, As, Bs, acc);

  int tid = threadIdx.x;
  int w = tid >> 6, l = tid & 63, lr = l & 15, lg = l >> 4;
  int wr = w >> 1, wc = w & 1;
  int z2 = col0 >> 9;  // 0=Q 1=K 2=V (uniform per block)
  if (z2 < 2) {
    bf16* O = z2 ? Kb : Qb;
    const float* bias = z2 ? bk : bq;
    float qs = z2 ? 1.0f : INV_SQRT_D;
#pragma unroll
    for (int n = 0; n < 4; ++n) {
      int cg = (col0 & 511) + wc * 64 + n * 16 + lr;
      float bi = bias[cg];
#pragma unroll
      for (int m = 0; m < 4; ++m) {
        int rg = row0 + wr * 64 + m * 16 + lg * 4;
#pragma unroll
        for (int r = 0; r < 4; ++r)
          O[(size_t)(rg + r) * DMODEL + cg] = (bf16)((acc[m][n][r] + bi) * qs);
      }
    }
  } else {
    // V: store transposed Vt[b][h][e][s]
#pragma unroll
    for (int n = 0; n < 4; ++n) {
      int ep = (col0 & 511) + wc * 64 + n * 16 + lr;
      int h = ep >> 6, e = ep & 63;
      float bi = bv[ep];
#pragma unroll
      for (int m = 0; m < 4; ++m) {
        int rg = row0 + wr * 64 + m * 16 + lg * 4;
        int b = rg >> 11, s0 = rg & 2047;
        bf16x4v pk;
#pragma unroll
        for (int r = 0; r < 4; ++r) pk[r] = (bf16)(acc[m][n][r] + bi);
        *(bf16x4v*)(Vt + ((size_t)((b * 8 + h) * 64 + e)) * S_LEN + s0) = pk;
      }
    }
  }
}

// Wo GEMM + bias + residual, f32 out.
__global__ __launch_bounds__(256) void gemm_wo(
    const bf16* __restrict__ A, const bf16* __restrict__ W,
    const float* __restrict__ bo, const float* __restrict__ embed,
    float* __restrict__ X) {
  __shared__ __align__(16) bf16 As[128 * 64];
  __shared__ __align__(16) bf16 Bs[128 * 64];
  int row0 = blockIdx.x * 128, col0 = blockIdx.y * 128;
  f32x4 acc[4][4] = {};
  gemm128_core(A, W, row0, col0, As, Bs, acc);

  int tid = threadIdx.x;
  int w = tid >> 6, l = tid & 63, lr = l & 15, lg = l >> 4;
  int wr = w >> 1, wc = w & 1;
#pragma unroll
  for (int n = 0; n < 4; ++n) {
    int cg = col0 + wc * 64 + n * 16 + lr;
    float bi = bo[cg];
#pragma unroll
    for (int m = 0; m < 4; ++m) {
      int rg = row0 + wr * 64 + m * 16 + lg * 4;
#pragma unroll
      for (int r = 0; r < 4; ++r)
        X[(size_t)(rg + r) * DMODEL + cg] =
            acc[m][n][r] + bi + embed[(size_t)(rg + r) * DMODEL + cg];
    }
  }
}

// SUF[bh][j][e] = sum_{t >= 16j} V[t][e], j = 0..128 (SUF[128]=0).
__global__ __launch_bounds__(256) void suf_kernel(const bf16* __restrict__ Vt,
                                                  float* __restrict__ SUF) {
  int bh = blockIdx.x;
  int e = threadIdx.x & 63;
  int seg = threadIdx.x >> 6;
  __shared__ float segtot[4][64];
  const bf16* vrow = Vt + ((size_t)bh * 64 + e) * S_LEN;
  float loc[32];
  float carry = 0.f;
#pragma unroll
  for (int j = 31; j >= 0; --j) {
    int jj = seg * 32 + j;
    bf16x8 a = *(const bf16x8*)(vrow + jj * 16);
    bf16x8 b2 = *(const bf16x8*)(vrow + jj * 16 + 8);
    float s = 0.f;
#pragma unroll
    for (int k = 0; k < 8; ++k) s += (float)a[k] + (float)b2[k];
    carry += s;
    loc[j] = carry;
  }
  segtot[seg][e] = carry;
  __syncthreads();
  float add = 0.f;
  for (int s2 = seg + 1; s2 < 4; ++s2) add += segtot[s2][e];
  float* srow = SUF + (size_t)bh * 129 * 64 + e;
#pragma unroll
  for (int j = 0; j < 32; ++j) srow[(size_t)(seg * 32 + j) * 64] = loc[j] + add;
  if (threadIdx.x < 64) srow[(size_t)128 * 64] = 0.f;
}

// Flash attention v2: QBLK=128, 8 waves x 16 q-rows, KVBLK=64,
// double-buffered GLDS staging, 1 barrier/iter, flat softmax.
__global__ __launch_bounds__(512) void flash_attn(
    const bf16* __restrict__ Qb, const bf16* __restrict__ Kb,
    const bf16* __restrict__ Vt, const float* __restrict__ SUF,
    bf16* __restrict__ attO) {
  int bh = blockIdx.y;
  int b = bh >> 3, h = bh & 7;
  int qi = (int)gridDim.x - 1 - (int)blockIdx.x;  // largest-work blocks first
  int qb = qi * 128;
  int tid = threadIdx.x;
  int w = tid >> 6, l = tid & 63, lr = l & 15, lg = l >> 4;

  __shared__ __align__(16) bf16 kl[2][64 * 64];   // K tile [t][e], swizzled
  __shared__ __align__(16) bf16 vl[2][64 * 64];   // V^T tile [e][t], swizzled
  __shared__ __align__(16) bf16 pl[8][16 * 64];   // per-wave P tile [s][t], swizzled

  int srow = qb + 16 * w + lr;
  const bf16* qptr = Qb + ((size_t)(b * S_LEN) + srow) * DMODEL + h * 64 + lg * 8;
  bf16x8 aq0 = *(const bf16x8*)(qptr);
  bf16x8 aq1 = *(const bf16x8*)(qptr + 32);

  float lsum[4] = {0.f, 0.f, 0.f, 0.f};
  f32x4 acc[4] = {};

  int tmax_w = qb + 16 * w + 16;  // analytic tail starts here for this wave
  int nt = (qb + 128) >> 6;       // KV-tile iterations

  // staging: thread -> (row 0..63, chunk 0..7); source pre-swizzled chunk^=(row&7)
  int grow = tid >> 3, gch = tid & 7;
  int sch = ((gch ^ (grow & 7)) << 3);
  const bf16* Kg = Kb + ((size_t)(b * S_LEN) + grow) * DMODEL + h * 64 + sch;
  const bf16* Vg = Vt + ((size_t)(bh * 64) + grow) * S_LEN + sch;
  int sdst = w * 1024;  // wave-uniform LDS dest (lane*16 implicit)

  // fragment-read swizzle offsets
  int sw0 = (lg ^ (lr & 7)) << 4;
  int sw4 = sw0 ^ 0x40;
  char* plb = (char*)pl[w];

  // prologue: stage tile 0 into buf 0
  GLDS(Kg, (char*)kl[0] + sdst);
  GLDS(Vg, (char*)vl[0] + sdst);
  asm volatile("s_waitcnt vmcnt(0)" ::: "memory");
  __syncthreads();

  int cur = 0;
  for (int it = 0; it < nt; ++it) {
    int t0 = it << 6;
    if (it + 1 < nt) {
      GLDS(Kg + (size_t)(t0 + 64) * DMODEL, (char*)kl[cur ^ 1] + sdst);
      GLDS(Vg + (t0 + 64), (char*)vl[cur ^ 1] + sdst);
    }
    if (t0 < tmax_w) {  // wave-uniform skip of fully-masked tiles
      char* klb = (char*)kl[cur];
      char* vlb = (char*)vl[cur];

      f32x4 sfrag[4];
      const f32x4 fz = {0.f, 0.f, 0.f, 0.f};
#pragma unroll
      for (int c = 0; c < 4; ++c) {
        int rb = (16 * c + lr) * 128;
        bf16x8 bk0 = *(const bf16x8*)(klb + rb + sw0);
        bf16x8 bk1 = *(const bf16x8*)(klb + rb + sw4);
        f32x4 t = __builtin_amdgcn_mfma_f32_16x16x32_bf16(aq0, bk0, fz, 0, 0, 0);
        sfrag[c] = __builtin_amdgcn_mfma_f32_16x16x32_bf16(aq1, bk1, t, 0, 0, 0);
      }

      bool interior = (t0 + 64 <= qb + 16 * w);  // all tg <= sg for this wave
#pragma unroll
      for (int r = 0; r < 4; ++r) {
        int sg = qb + 16 * w + lg * 4 + r;
        int row = lg * 4 + r;
        int pbase = row * 128 + ((lr & 7) << 1);
        int xorv = row & 7;
        float psum = 0.f;
#pragma unroll
        for (int c = 0; c < 4; ++c) {
          int tg = t0 + 16 * c + lr;
          float x = interior ? sfrag[c][r]
                             : ((tg <= sg) ? sfrag[c][r] : ((tg < tmax_w) ? 0.f : -1e30f));
          float p = __expf(x);
          psum += p;
          int chunk = 2 * c + (lr >> 3);
          *(bf16*)(plb + pbase + (((chunk ^ xorv) << 4))) = (bf16)p;
        }
        lsum[r] += psum;
      }

      bf16x8 pa0 = *(const bf16x8*)(plb + lr * 128 + sw0);
      bf16x8 pa1 = *(const bf16x8*)(plb + lr * 128 + sw4);
#pragma unroll
      for (int c = 0; c < 4; ++c) {
        int rb = (16 * c + lr) * 128;
        bf16x8 bv0 = *(const bf16x8*)(vlb + rb + sw0);
        bf16x8 bv1 = *(const bf16x8*)(vlb + rb + sw4);
        acc[c] = __builtin_amdgcn_mfma_f32_16x16x32_bf16(pa0, bv0, acc[c], 0, 0, 0);
        acc[c] = __builtin_amdgcn_mfma_f32_16x16x32_bf16(pa1, bv1, acc[c], 0, 0, 0);
      }
    }
    asm volatile("s_waitcnt vmcnt(0)" ::: "memory");
    __syncthreads();
    cur ^= 1;
  }

  // single end-of-kernel reduction of lsum across the 16 t-lanes
#pragma unroll
  for (int r = 0; r < 4; ++r) {
#pragma unroll
    for (int d = 1; d < 16; d <<= 1) lsum[r] += __shfl_xor(lsum[r], d, 64);
  }

  int j16 = tmax_w >> 4;
  const float* suf = SUF + ((size_t)bh * 129 + j16) * 64;
  float cnt = (float)(S_LEN - tmax_w);
  float sufe[4];
#pragma unroll
  for (int c = 0; c < 4; ++c) sufe[c] = suf[16 * c + lr];
#pragma unroll
  for (int r = 0; r < 4; ++r) {
    float inv = 1.f / (lsum[r] + cnt);
    int sg = qb + 16 * w + lg * 4 + r;
#pragma unroll
    for (int c = 0; c < 4; ++c) {
      float o = (acc[c][r] + sufe[c]) * inv;
      attO[((size_t)(b * S_LEN) + sg) * DMODEL + h * 64 + 16 * c + lr] = (bf16)o;
    }
  }
}

__global__ __launch_bounds__(256) void ln_kernel(const float* __restrict__ x,
                                                 const float* __restrict__ gamma,
                                                 const float* __restrict__ beta,
                                                 float* __restrict__ out) {
  int row = blockIdx.x * 4 + (threadIdx.x >> 6);
  int l = threadIdx.x & 63;
  const float4* xr = reinterpret_cast<const float4*>(x + (size_t)row * DMODEL) + l * 2;
  float4 v0 = xr[0], v1 = xr[1];
  float s = v0.x + v0.y + v0.z + v0.w + v1.x + v1.y + v1.z + v1.w;
  float s2 = v0.x * v0.x + v0.y * v0.y + v0.z * v0.z + v0.w * v0.w +
             v1.x * v1.x + v1.y * v1.y + v1.z * v1.z + v1.w * v1.w;
#pragma unroll
  for (int d = 1; d < 64; d <<= 1) {
    s += __shfl_xor(s, d, 64);
    s2 += __shfl_xor(s2, d, 64);
  }
  float mean = s * (1.f / 512.f);
  float var = s2 * (1.f / 512.f) - mean * mean;
  float rstd = rsqrtf(var + 1e-5f);
  const float4* g4 = reinterpret_cast<const float4*>(gamma) + l * 2;
  const float4* b4 = reinterpret_cast<const float4*>(beta) + l * 2;
  float4 g0 = g4[0], g1 = g4[1], bb0 = b4[0], bb1 = b4[1];
  float4 o0, o1;
  o0.x = (v0.x - mean) * rstd * g0.x + bb0.x;
  o0.y = (v0.y - mean) * rstd * g0.y + bb0.y;
  o0.z = (v0.z - mean) * rstd * g0.z + bb0.z;
  o0.w = (v0.w - mean) * rstd * g0.w + bb0.w;
  o1.x = (v1.x - mean) * rstd * g1.x + bb1.x;
  o1.y = (v1.y - mean) * rstd * g1.y + bb1.y;
  o1.z = (v1.z - mean) * rstd * g1.z + bb1.z;
  o1.w = (v1.w - mean) * rstd * g1.w + bb1.w;
  float4* orow = reinterpret_cast<float4*>(out + (size_t)row * DMODEL) + l * 2;
  orow[0] = o0;
  orow[1] = o1;
}

extern "C" void kernel_launch(void* const* d_in, const int* in_sizes, int n_in,
                              void* d_out, int out_size, void* d_ws, size_t ws_size,
                              hipStream_t stream) {
  const float* embed = (const float*)d_in[0];
  const float* Wq = (const float*)d_in[1];
  const float* bq = (const float*)d_in[2];
  const float* Wk = (const float*)d_in[3];
  const float* bk = (const float*)d_in[4];
  const float* Wv = (const float*)d_in[5];
  const float* bv = (const float*)d_in[6];
  const float* Wo = (const float*)d_in[7];
  const float* bo = (const float*)d_in[8];
  const float* gamma = (const float*)d_in[9];
  const float* beta = (const float*)d_in[10];
  float* out = (float*)d_out;

  char* ws = (char*)d_ws;
  size_t off = 0;
  auto alc = [&](size_t b) { size_t o = off; off += (b + 255) & ~(size_t)255; return o; };
  bf16* Eb    = (bf16*)(ws + alc(8192ull * 512 * 2));
  bf16* Wqkv  = (bf16*)(ws + alc(1536ull * 512 * 2));
  bf16* Wob   = (bf16*)(ws + alc(512ull * 512 * 2));
  bf16* Qb    = (bf16*)(ws + alc(8192ull * 512 * 2));
  bf16* Kb    = (bf16*)(ws + alc(8192ull * 512 * 2));
  bf16* Vt    = (bf16*)(ws + alc(8192ull * 512 * 2));
  float* SUF  = (float*)(ws + alc(32ull * 129 * 64 * 4));
  bf16* AttO  = (bf16*)(ws + alc(8192ull * 512 * 2));
  float* Xb   = (float*)(ws + alc(8192ull * 512 * 4));
  (void)ws_size; (void)n_in; (void)in_sizes; (void)out_size;

  cast_f32_bf16<<<4096, 256, 0, stream>>>(embed, Eb, 4194304 / 4);
  cast4_f32_bf16<<<dim3(256, 4), 256, 0, stream>>>(
      Wq, Wk, Wv, Wo, Wqkv, Wqkv + 512ull * 512, Wqkv + 1024ull * 512, Wob);

  gemm_qkv<<<dim3(64, 12), 256, 0, stream>>>(Eb, Wqkv, bq, bk, bv, Qb, Kb, Vt);
  suf_kernel<<<32, 256, 0, stream>>>(Vt, SUF);
  flash_attn<<<dim3(16, 32), 512, 0, stream>>>(Qb, Kb, Vt, SUF, AttO);
  gemm_wo<<<dim3(64, 4), 256, 0, stream>>>(AttO, Wob, bo, embed, Xb);
  ln_kernel<<<2048, 256, 0, stream>>>(Xb, gamma, beta, out);
}

// Round 6
// 113.903 us; speedup vs baseline: 3.2025x; 1.1430x over previous
//
#include <hip/hip_runtime.h>
#include <hip/hip_bf16.h>

// B=4, S=2048, D=512, H=8, DH=64
// m97-structure 128x128 LDS-staged GEMMs (global_load_lds w16 + XOR swizzle),
// flat-softmax flash attention (scores analytically bounded; tril zeros pin max~0),
// masked tail folded analytically via V suffix sums.
// flash v3: 8 waves = two complementary q-tiles (16+p big / 15-p small) sharing one
// KV sweep; exp2-folded scale (p = single v_exp_f32); double-buffered GLDS staging.

typedef __bf16 bf16;
typedef __bf16 bf16x8 __attribute__((ext_vector_type(8)));
typedef __bf16 bf16x4v __attribute__((ext_vector_type(4)));
typedef float f32x4 __attribute__((ext_vector_type(4)));

#define S_LEN 2048
#define DMODEL 512
// log2(e)/sqrt(512): Q pre-scale so softmax exp is a bare exp2
#define QSCALE 0.06375870914f

#define GLDS(g, l) __builtin_amdgcn_global_load_lds(                  \
    (const __attribute__((address_space(1))) void*)(g),               \
    (__attribute__((address_space(3))) void*)(l), 16, 0, 0)

__global__ __launch_bounds__(256) void cast_f32_bf16(const float* __restrict__ in,
                                                     bf16* __restrict__ out, int n4) {
  int i = blockIdx.x * blockDim.x + threadIdx.x;
  if (i < n4) {
    float4 v = reinterpret_cast<const float4*>(in)[i];
    bf16x4v o;
    o[0] = (bf16)v.x; o[1] = (bf16)v.y; o[2] = (bf16)v.z; o[3] = (bf16)v.w;
    *reinterpret_cast<bf16x4v*>(out + (size_t)i * 4) = o;
  }
}

// Wq,Wk,Wv -> contiguous Wqkv[1536][512]; Wo -> Wob
__global__ __launch_bounds__(256) void cast4_f32_bf16(
    const float* __restrict__ a0, const float* __restrict__ a1,
    const float* __restrict__ a2, const float* __restrict__ a3,
    bf16* __restrict__ o0, bf16* __restrict__ o1,
    bf16* __restrict__ o2, bf16* __restrict__ o3) {
  int y = blockIdx.y;
  const float* in = (y == 0) ? a0 : (y == 1) ? a1 : (y == 2) ? a2 : a3;
  bf16* out = (y == 0) ? o0 : (y == 1) ? o1 : (y == 2) ? o2 : o3;
  int i = blockIdx.x * blockDim.x + threadIdx.x;
  float4 v = reinterpret_cast<const float4*>(in)[i];
  bf16x4v o;
  o[0] = (bf16)v.x; o[1] = (bf16)v.y; o[2] = (bf16)v.z; o[3] = (bf16)v.w;
  *reinterpret_cast<bf16x4v*>(out + (size_t)i * 4) = o;
}

// ---- 128x128 tile GEMM core: C = A[M,512] * Bw[N,512]^T, K=512, BK=64 ----
__device__ __forceinline__ void gemm128_core(
    const bf16* __restrict__ A, const bf16* __restrict__ Bw,
    int row0, int col0, bf16* As, bf16* Bs, f32x4 (&acc)[4][4]) {
  int tid = threadIdx.x;
  int w = tid >> 6, l = tid & 63, lr = l & 15, lg = l >> 4;
  int wr = w >> 1, wc = w & 1;

  int srow = w * 8 + (l >> 3);
  int scol = ((l & 7) ^ (srow & 7)) << 3;
  const bf16* ga = A + (size_t)(row0 + srow) * DMODEL + scol;
  const bf16* gb = Bw + (size_t)(col0 + srow) * DMODEL + scol;
  char* asb = (char*)As;
  char* bsb = (char*)Bs;
  int sbase = w * 1024;

  int aoff[4], boff[4];
#pragma unroll
  for (int m = 0; m < 4; ++m) {
    aoff[m] = (wr * 64 + m * 16 + lr) * 128 + (((lg ^ (lr & 7))) << 4);
    boff[m] = (wc * 64 + m * 16 + lr) * 128 + (((lg ^ (lr & 7))) << 4);
  }

  for (int k0 = 0; k0 < DMODEL; k0 += 64) {
#pragma unroll
    for (int qt = 0; qt < 4; ++qt) {
      GLDS(ga + (size_t)qt * 32 * DMODEL, asb + qt * 4096 + sbase);
      GLDS(gb + (size_t)qt * 32 * DMODEL, bsb + qt * 4096 + sbase);
    }
    ga += 64; gb += 64;
    __syncthreads();

    bf16x8 af[2][4], bfv[2][4];
#pragma unroll
    for (int m = 0; m < 4; ++m) {
      af[0][m] = *(const bf16x8*)(asb + aoff[m]);
      af[1][m] = *(const bf16x8*)(asb + (aoff[m] ^ 0x40));
      bfv[0][m] = *(const bf16x8*)(bsb + boff[m]);
      bfv[1][m] = *(const bf16x8*)(bsb + (boff[m] ^ 0x40));
    }
#pragma unroll
    for (int m = 0; m < 4; ++m)
#pragma unroll
      for (int n = 0; n < 4; ++n) {
        acc[m][n] = __builtin_amdgcn_mfma_f32_16x16x32_bf16(af[0][m], bfv[0][n], acc[m][n], 0, 0, 0);
        acc[m][n] = __builtin_amdgcn_mfma_f32_16x16x32_bf16(af[1][m], bfv[1][n], acc[m][n], 0, 0, 0);
      }
    __syncthreads();
  }
}

// Fused QKV GEMM: Wqkv[1536][512]; col-tiles 0-3 = Q, 4-7 = K, 8-11 = V.
__global__ __launch_bounds__(256) void gemm_qkv(
    const bf16* __restrict__ A, const bf16* __restrict__ Wqkv,
    const float* __restrict__ bq, const float* __restrict__ bk, const float* __restrict__ bv,
    bf16* __restrict__ Qb, bf16* __restrict__ Kb, bf16* __restrict__ Vt) {
  __shared__ __align__(16) bf16 As[128 * 64];
  __shared__ __align__(16) bf16 Bs[128 * 64];
  int row0 = blockIdx.x * 128, col0 = blockIdx.y * 128;
  f32x4 acc[4][4] = {};
  gemm128_core(A, Wqkv, row0, col0, As, Bs, acc);

  int tid = threadIdx.x;
  int w = tid >> 6, l = tid & 63, lr = l & 15, lg = l >> 4;
  int wr = w >> 1, wc = w & 1;
  int z2 = col0 >> 9;  // 0=Q 1=K 2=V (uniform per block)
  if (z2 < 2) {
    bf16* O = z2 ? Kb : Qb;
    const float* bias = z2 ? bk : bq;
    float qs = z2 ? 1.0f : QSCALE;
#pragma unroll
    for (int n = 0; n < 4; ++n) {
      int cg = (col0 & 511) + wc * 64 + n * 16 + lr;
      float bi = bias[cg];
#pragma unroll
      for (int m = 0; m < 4; ++m) {
        int rg = row0 + wr * 64 + m * 16 + lg * 4;
#pragma unroll
        for (int r = 0; r < 4; ++r)
          O[(size_t)(rg + r) * DMODEL + cg] = (bf16)((acc[m][n][r] + bi) * qs);
      }
    }
  } else {
    // V: store transposed Vt[b][h][e][s]
#pragma unroll
    for (int n = 0; n < 4; ++n) {
      int ep = (col0 & 511) + wc * 64 + n * 16 + lr;
      int h = ep >> 6, e = ep & 63;
      float bi = bv[ep];
#pragma unroll
      for (int m = 0; m < 4; ++m) {
        int rg = row0 + wr * 64 + m * 16 + lg * 4;
        int b = rg >> 11, s0 = rg & 2047;
        bf16x4v pk;
#pragma unroll
        for (int r = 0; r < 4; ++r) pk[r] = (bf16)(acc[m][n][r] + bi);
        *(bf16x4v*)(Vt + ((size_t)((b * 8 + h) * 64 + e)) * S_LEN + s0) = pk;
      }
    }
  }
}

// Wo GEMM + bias + residual, f32 out.
__global__ __launch_bounds__(256) void gemm_wo(
    const bf16* __restrict__ A, const bf16* __restrict__ W,
    const float* __restrict__ bo, const float* __restrict__ embed,
    float* __restrict__ X) {
  __shared__ __align__(16) bf16 As[128 * 64];
  __shared__ __align__(16) bf16 Bs[128 * 64];
  int row0 = blockIdx.x * 128, col0 = blockIdx.y * 128;
  f32x4 acc[4][4] = {};
  gemm128_core(A, W, row0, col0, As, Bs, acc);

  int tid = threadIdx.x;
  int w = tid >> 6, l = tid & 63, lr = l & 15, lg = l >> 4;
  int wr = w >> 1, wc = w & 1;
#pragma unroll
  for (int n = 0; n < 4; ++n) {
    int cg = col0 + wc * 64 + n * 16 + lr;
    float bi = bo[cg];
#pragma unroll
    for (int m = 0; m < 4; ++m) {
      int rg = row0 + wr * 64 + m * 16 + lg * 4;
#pragma unroll
      for (int r = 0; r < 4; ++r)
        X[(size_t)(rg + r) * DMODEL + cg] =
            acc[m][n][r] + bi + embed[(size_t)(rg + r) * DMODEL + cg];
    }
  }
}

// SUF[bh][j][e] = sum_{t >= 16j} V[t][e], j = 0..128 (SUF[128]=0).
__global__ __launch_bounds__(256) void suf_kernel(const bf16* __restrict__ Vt,
                                                  float* __restrict__ SUF) {
  int bh = blockIdx.x;
  int e = threadIdx.x & 63;
  int seg = threadIdx.x >> 6;
  __shared__ float segtot[4][64];
  const bf16* vrow = Vt + ((size_t)bh * 64 + e) * S_LEN;
  float loc[32];
  float carry = 0.f;
#pragma unroll
  for (int j = 31; j >= 0; --j) {
    int jj = seg * 32 + j;
    bf16x8 a = *(const bf16x8*)(vrow + jj * 16);
    bf16x8 b2 = *(const bf16x8*)(vrow + jj * 16 + 8);
    float s = 0.f;
#pragma unroll
    for (int k = 0; k < 8; ++k) s += (float)a[k] + (float)b2[k];
    carry += s;
    loc[j] = carry;
  }
  segtot[seg][e] = carry;
  __syncthreads();
  float add = 0.f;
  for (int s2 = seg + 1; s2 < 4; ++s2) add += segtot[s2][e];
  float* srow = SUF + (size_t)bh * 129 * 64 + e;
#pragma unroll
  for (int j = 0; j < 32; ++j) srow[(size_t)(seg * 32 + j) * 64] = loc[j] + add;
  if (threadIdx.x < 64) srow[(size_t)128 * 64] = 0.f;
}

// Flash attention v3: 8 waves, waves 0-3 = big q-tile (16+p), waves 4-7 = small
// q-tile (15-p), one shared KV sweep (nt = 17+p), double-buffered GLDS staging,
// flat softmax via bare exp2 (scale folded into Q).
__global__ __launch_bounds__(512) void flash_attn(
    const bf16* __restrict__ Qb, const bf16* __restrict__ Kb,
    const bf16* __restrict__ Vt, const float* __restrict__ SUF,
    bf16* __restrict__ attO) {
  int bh = blockIdx.y;
  int b = bh >> 3, h = bh & 7;
  int p = (int)gridDim.x - 1 - (int)blockIdx.x;  // 15..0, biggest first
  int tid = threadIdx.x;
  int w = tid >> 6, l = tid & 63, lr = l & 15, lg = l >> 4;
  int wsub = w & 3;
  int qtile = (w < 4) ? (16 + p) : (15 - p);
  int qb = qtile * 64;
  int nt = 17 + p;  // block-uniform KV-tile count (covers big tile's range)

  __shared__ __align__(16) bf16 kl[2][64 * 64];   // K tile [t][e], swizzled
  __shared__ __align__(16) bf16 vl[2][64 * 64];   // V^T tile [e][t], swizzled
  __shared__ __align__(16) bf16 pl[8][16 * 64];   // per-wave P tile [s][t], swizzled

  int srow = qb + 16 * wsub + lr;
  const bf16* qptr = Qb + ((size_t)(b * S_LEN) + srow) * DMODEL + h * 64 + lg * 8;
  bf16x8 aq0 = *(const bf16x8*)(qptr);
  bf16x8 aq1 = *(const bf16x8*)(qptr + 32);

  float lsum[4] = {0.f, 0.f, 0.f, 0.f};
  f32x4 acc[4] = {};

  int tmax_w = qb + 16 * wsub + 16;  // analytic tail starts here for this wave

  // staging: thread -> (row 0..63, chunk 0..7); source pre-swizzled chunk^=(row&7)
  int grow = tid >> 3, gch = tid & 7;
  int sch = ((gch ^ (grow & 7)) << 3);
  const bf16* Kg = Kb + ((size_t)(b * S_LEN) + grow) * DMODEL + h * 64 + sch;
  const bf16* Vg = Vt + ((size_t)(bh * 64) + grow) * S_LEN + sch;
  int sdst = w * 1024;  // wave-uniform LDS dest (lane*16 implicit)

  // fragment-read swizzle offsets
  int sw0 = (lg ^ (lr & 7)) << 4;
  int sw4 = sw0 ^ 0x40;
  char* plb = (char*)pl[w];

  // prologue: stage tile 0 into buf 0
  GLDS(Kg, (char*)kl[0] + sdst);
  GLDS(Vg, (char*)vl[0] + sdst);
  asm volatile("s_waitcnt vmcnt(0)" ::: "memory");
  __syncthreads();

  int cur = 0;
  for (int it = 0; it < nt; ++it) {
    int t0 = it << 6;
    if (it + 1 < nt) {
      GLDS(Kg + (size_t)(t0 + 64) * DMODEL, (char*)kl[cur ^ 1] + sdst);
      GLDS(Vg + (t0 + 64), (char*)vl[cur ^ 1] + sdst);
    }
    if (t0 < tmax_w) {  // wave-uniform skip of fully-masked tiles
      char* klb = (char*)kl[cur];
      char* vlb = (char*)vl[cur];

      f32x4 sfrag[4];
      const f32x4 fz = {0.f, 0.f, 0.f, 0.f};
#pragma unroll
      for (int c = 0; c < 4; ++c) {
        int rb = (16 * c + lr) * 128;
        bf16x8 bk0 = *(const bf16x8*)(klb + rb + sw0);
        bf16x8 bk1 = *(const bf16x8*)(klb + rb + sw4);
        f32x4 t = __builtin_amdgcn_mfma_f32_16x16x32_bf16(aq0, bk0, fz, 0, 0, 0);
        sfrag[c] = __builtin_amdgcn_mfma_f32_16x16x32_bf16(aq1, bk1, t, 0, 0, 0);
      }

      if (t0 + 64 <= qb + 16 * wsub) {
        // interior: no masking at all
#pragma unroll
        for (int r = 0; r < 4; ++r) {
          int row = lg * 4 + r;
          int pbase = row * 128 + ((lr & 7) << 1);
          int xorv = row & 7;
          float psum = 0.f;
#pragma unroll
          for (int c = 0; c < 4; ++c) {
            float pv = exp2f(sfrag[c][r]);
            psum += pv;
            int chunk = 2 * c + (lr >> 3);
            *(bf16*)(plb + pbase + (((chunk ^ xorv) << 4))) = (bf16)pv;
          }
          lsum[r] += psum;
        }
      } else {
        // boundary tile: per-element mask (x=0 inside tril-zero region, -inf past tail)
#pragma unroll
        for (int r = 0; r < 4; ++r) {
          int sg = qb + 16 * wsub + lg * 4 + r;
          int row = lg * 4 + r;
          int pbase = row * 128 + ((lr & 7) << 1);
          int xorv = row & 7;
          float psum = 0.f;
#pragma unroll
          for (int c = 0; c < 4; ++c) {
            int tg = t0 + 16 * c + lr;
            float x = (tg <= sg) ? sfrag[c][r] : ((tg < tmax_w) ? 0.f : -1e30f);
            float pv = exp2f(x);
            psum += pv;
            int chunk = 2 * c + (lr >> 3);
            *(bf16*)(plb + pbase + (((chunk ^ xorv) << 4))) = (bf16)pv;
          }
          lsum[r] += psum;
        }
      }

      bf16x8 pa0 = *(const bf16x8*)(plb + lr * 128 + sw0);
      bf16x8 pa1 = *(const bf16x8*)(plb + lr * 128 + sw4);
#pragma unroll
      for (int c = 0; c < 4; ++c) {
        int rb = (16 * c + lr) * 128;
        bf16x8 bv0 = *(const bf16x8*)(vlb + rb + sw0);
        bf16x8 bv1 = *(const bf16x8*)(vlb + rb + sw4);
        acc[c] = __builtin_amdgcn_mfma_f32_16x16x32_bf16(pa0, bv0, acc[c], 0, 0, 0);
        acc[c] = __builtin_amdgcn_mfma_f32_16x16x32_bf16(pa1, bv1, acc[c], 0, 0, 0);
      }
    }
    asm volatile("s_waitcnt vmcnt(0)" ::: "memory");
    __syncthreads();
    cur ^= 1;
  }

  // single end-of-kernel reduction of lsum across the 16 t-lanes
#pragma unroll
  for (int r = 0; r < 4; ++r) {
#pragma unroll
    for (int d = 1; d < 16; d <<= 1) lsum[r] += __shfl_xor(lsum[r], d, 64);
  }

  int j16 = tmax_w >> 4;
  const float* suf = SUF + ((size_t)bh * 129 + j16) * 64;
  float cnt = (float)(S_LEN - tmax_w);
  float sufe[4];
#pragma unroll
  for (int c = 0; c < 4; ++c) sufe[c] = suf[16 * c + lr];
#pragma unroll
  for (int r = 0; r < 4; ++r) {
    float inv = 1.f / (lsum[r] + cnt);
    int sg = qb + 16 * wsub + lg * 4 + r;
#pragma unroll
    for (int c = 0; c < 4; ++c) {
      float o = (acc[c][r] + sufe[c]) * inv;
      attO[((size_t)(b * S_LEN) + sg) * DMODEL + h * 64 + 16 * c + lr] = (bf16)o;
    }
  }
}

__global__ __launch_bounds__(256) void ln_kernel(const float* __restrict__ x,
                                                 const float* __restrict__ gamma,
                                                 const float* __restrict__ beta,
                                                 float* __restrict__ out) {
  int row = blockIdx.x * 4 + (threadIdx.x >> 6);
  int l = threadIdx.x & 63;
  const float4* xr = reinterpret_cast<const float4*>(x + (size_t)row * DMODEL) + l * 2;
  float4 v0 = xr[0], v1 = xr[1];
  float s = v0.x + v0.y + v0.z + v0.w + v1.x + v1.y + v1.z + v1.w;
  float s2 = v0.x * v0.x + v0.y * v0.y + v0.z * v0.z + v0.w * v0.w +
             v1.x * v1.x + v1.y * v1.y + v1.z * v1.z + v1.w * v1.w;
#pragma unroll
  for (int d = 1; d < 64; d <<= 1) {
    s += __shfl_xor(s, d, 64);
    s2 += __shfl_xor(s2, d, 64);
  }
  float mean = s * (1.f / 512.f);
  float var = s2 * (1.f / 512.f) - mean * mean;
  float rstd = rsqrtf(var + 1e-5f);
  const float4* g4 = reinterpret_cast<const float4*>(gamma) + l * 2;
  const float4* b4 = reinterpret_cast<const float4*>(beta) + l * 2;
  float4 g0 = g4[0], g1 = g4[1], bb0 = b4[0], bb1 = b4[1];
  float4 o0, o1;
  o0.x = (v0.x - mean) * rstd * g0.x + bb0.x;
  o0.y = (v0.y - mean) * rstd * g0.y + bb0.y;
  o0.z = (v0.z - mean) * rstd * g0.z + bb0.z;
  o0.w = (v0.w - mean) * rstd * g0.w + bb0.w;
  o1.x = (v1.x - mean) * rstd * g1.x + bb1.x;
  o1.y = (v1.y - mean) * rstd * g1.y + bb1.y;
  o1.z = (v1.z - mean) * rstd * g1.z + bb1.z;
  o1.w = (v1.w - mean) * rstd * g1.w + bb1.w;
  float4* orow = reinterpret_cast<float4*>(out + (size_t)row * DMODEL) + l * 2;
  orow[0] = o0;
  orow[1] = o1;
}

extern "C" void kernel_launch(void* const* d_in, const int* in_sizes, int n_in,
                              void* d_out, int out_size, void* d_ws, size_t ws_size,
                              hipStream_t stream) {
  const float* embed = (const float*)d_in[0];
  const float* Wq = (const float*)d_in[1];
  const float* bq = (const float*)d_in[2];
  const float* Wk = (const float*)d_in[3];
  const float* bk = (const float*)d_in[4];
  const float* Wv = (const float*)d_in[5];
  const float* bv = (const float*)d_in[6];
  const float* Wo = (const float*)d_in[7];
  const float* bo = (const float*)d_in[8];
  const float* gamma = (const float*)d_in[9];
  const float* beta = (const float*)d_in[10];
  float* out = (float*)d_out;

  char* ws = (char*)d_ws;
  size_t off = 0;
  auto alc = [&](size_t b) { size_t o = off; off += (b + 255) & ~(size_t)255; return o; };
  bf16* Eb    = (bf16*)(ws + alc(8192ull * 512 * 2));
  bf16* Wqkv  = (bf16*)(ws + alc(1536ull * 512 * 2));
  bf16* Wob   = (bf16*)(ws + alc(512ull * 512 * 2));
  bf16* Qb    = (bf16*)(ws + alc(8192ull * 512 * 2));
  bf16* Kb    = (bf16*)(ws + alc(8192ull * 512 * 2));
  bf16* Vt    = (bf16*)(ws + alc(8192ull * 512 * 2));
  float* SUF  = (float*)(ws + alc(32ull * 129 * 64 * 4));
  bf16* AttO  = (bf16*)(ws + alc(8192ull * 512 * 2));
  float* Xb   = (float*)(ws + alc(8192ull * 512 * 4));
  (void)ws_size; (void)n_in; (void)in_sizes; (void)out_size;

  cast_f32_bf16<<<4096, 256, 0, stream>>>(embed, Eb, 4194304 / 4);
  cast4_f32_bf16<<<dim3(256, 4), 256, 0, stream>>>(
      Wq, Wk, Wv, Wo, Wqkv, Wqkv + 512ull * 512, Wqkv + 1024ull * 512, Wob);

  gemm_qkv<<<dim3(64, 12), 256, 0, stream>>>(Eb, Wqkv, bq, bk, bv, Qb, Kb, Vt);
  suf_kernel<<<32, 256, 0, stream>>>(Vt, SUF);
  flash_attn<<<dim3(16, 32), 512, 0, stream>>>(Qb, Kb, Vt, SUF, AttO);
  gemm_wo<<<dim3(64, 4), 256, 0, stream>>>(AttO, Wob, bo, embed, Xb);
  ln_kernel<<<2048, 256, 0, stream>>>(Xb, gamma, beta, out);
}

// Round 7
// 111.276 us; speedup vs baseline: 3.2780x; 1.0236x over previous
//
#include <hip/hip_runtime.h>
#include <hip/hip_bf16.h>

// B=4, S=2048, D=512, H=8, DH=64
// m97-structure 128x128 LDS-staged GEMMs (global_load_lds w16 + XOR swizzle),
// flat-softmax flash attention (scores analytically bounded; tril zeros pin max~0),
// masked tail folded analytically via V suffix sums.
// v4: merged cast kernel; bf16 Xb (gemm_wo out / ln in); suf 8-way; setprio on
// flash MFMA clusters.

typedef __bf16 bf16;
typedef __bf16 bf16x8 __attribute__((ext_vector_type(8)));
typedef __bf16 bf16x4v __attribute__((ext_vector_type(4)));
typedef float f32x4 __attribute__((ext_vector_type(4)));

#define S_LEN 2048
#define DMODEL 512
// log2(e)/sqrt(512): Q pre-scale so softmax exp is a bare exp2
#define QSCALE 0.06375870914f

#define GLDS(g, l) __builtin_amdgcn_global_load_lds(                  \
    (const __attribute__((address_space(1))) void*)(g),               \
    (__attribute__((address_space(3))) void*)(l), 16, 0, 0)

// One launch: embed (1,048,576 f4) then Wq,Wk,Wv,Wo (65,536 f4 each).
__global__ __launch_bounds__(256) void cast_all(
    const float* __restrict__ embed, const float* __restrict__ Wq,
    const float* __restrict__ Wk, const float* __restrict__ Wv,
    const float* __restrict__ Wo,
    bf16* __restrict__ Eb, bf16* __restrict__ Wqkv, bf16* __restrict__ Wob) {
  int i = blockIdx.x * 256 + threadIdx.x;
  const float* src;
  bf16* dst;
  int il;
  if (i < 1048576) {
    src = embed; dst = Eb; il = i;
  } else {
    int j = i - 1048576;
    int w = j >> 16;
    il = j & 65535;
    src = (w == 0) ? Wq : (w == 1) ? Wk : (w == 2) ? Wv : Wo;
    dst = (w == 3) ? Wob : Wqkv + (size_t)w * 262144;
  }
  float4 v = reinterpret_cast<const float4*>(src)[il];
  bf16x4v o;
  o[0] = (bf16)v.x; o[1] = (bf16)v.y; o[2] = (bf16)v.z; o[3] = (bf16)v.w;
  *reinterpret_cast<bf16x4v*>(dst + (size_t)il * 4) = o;
}

// ---- 128x128 tile GEMM core: C = A[M,512] * Bw[N,512]^T, K=512, BK=64 ----
__device__ __forceinline__ void gemm128_core(
    const bf16* __restrict__ A, const bf16* __restrict__ Bw,
    int row0, int col0, bf16* As, bf16* Bs, f32x4 (&acc)[4][4]) {
  int tid = threadIdx.x;
  int w = tid >> 6, l = tid & 63, lr = l & 15, lg = l >> 4;
  int wr = w >> 1, wc = w & 1;

  int srow = w * 8 + (l >> 3);
  int scol = ((l & 7) ^ (srow & 7)) << 3;
  const bf16* ga = A + (size_t)(row0 + srow) * DMODEL + scol;
  const bf16* gb = Bw + (size_t)(col0 + srow) * DMODEL + scol;
  char* asb = (char*)As;
  char* bsb = (char*)Bs;
  int sbase = w * 1024;

  int aoff[4], boff[4];
#pragma unroll
  for (int m = 0; m < 4; ++m) {
    aoff[m] = (wr * 64 + m * 16 + lr) * 128 + (((lg ^ (lr & 7))) << 4);
    boff[m] = (wc * 64 + m * 16 + lr) * 128 + (((lg ^ (lr & 7))) << 4);
  }

  for (int k0 = 0; k0 < DMODEL; k0 += 64) {
#pragma unroll
    for (int qt = 0; qt < 4; ++qt) {
      GLDS(ga + (size_t)qt * 32 * DMODEL, asb + qt * 4096 + sbase);
      GLDS(gb + (size_t)qt * 32 * DMODEL, bsb + qt * 4096 + sbase);
    }
    ga += 64; gb += 64;
    __syncthreads();

    bf16x8 af[2][4], bfv[2][4];
#pragma unroll
    for (int m = 0; m < 4; ++m) {
      af[0][m] = *(const bf16x8*)(asb + aoff[m]);
      af[1][m] = *(const bf16x8*)(asb + (aoff[m] ^ 0x40));
      bfv[0][m] = *(const bf16x8*)(bsb + boff[m]);
      bfv[1][m] = *(const bf16x8*)(bsb + (boff[m] ^ 0x40));
    }
#pragma unroll
    for (int m = 0; m < 4; ++m)
#pragma unroll
      for (int n = 0; n < 4; ++n) {
        acc[m][n] = __builtin_amdgcn_mfma_f32_16x16x32_bf16(af[0][m], bfv[0][n], acc[m][n], 0, 0, 0);
        acc[m][n] = __builtin_amdgcn_mfma_f32_16x16x32_bf16(af[1][m], bfv[1][n], acc[m][n], 0, 0, 0);
      }
    __syncthreads();
  }
}

// Fused QKV GEMM: Wqkv[1536][512]; col-tiles 0-3 = Q, 4-7 = K, 8-11 = V.
__global__ __launch_bounds__(256) void gemm_qkv(
    const bf16* __restrict__ A, const bf16* __restrict__ Wqkv,
    const float* __restrict__ bq, const float* __restrict__ bk, const float* __restrict__ bv,
    bf16* __restrict__ Qb, bf16* __restrict__ Kb, bf16* __restrict__ Vt) {
  __shared__ __align__(16) bf16 As[128 * 64];
  __shared__ __align__(16) bf16 Bs[128 * 64];
  int row0 = blockIdx.x * 128, col0 = blockIdx.y * 128;
  f32x4 acc[4][4] = {};
  gemm128_core(A, Wqkv, row0, col0, As, Bs, acc);

  int tid = threadIdx.x;
  int w = tid >> 6, l = tid & 63, lr = l & 15, lg = l >> 4;
  int wr = w >> 1, wc = w & 1;
  int z2 = col0 >> 9;  // 0=Q 1=K 2=V (uniform per block)
  if (z2 < 2) {
    bf16* O = z2 ? Kb : Qb;
    const float* bias = z2 ? bk : bq;
    float qs = z2 ? 1.0f : QSCALE;
#pragma unroll
    for (int n = 0; n < 4; ++n) {
      int cg = (col0 & 511) + wc * 64 + n * 16 + lr;
      float bi = bias[cg];
#pragma unroll
      for (int m = 0; m < 4; ++m) {
        int rg = row0 + wr * 64 + m * 16 + lg * 4;
#pragma unroll
        for (int r = 0; r < 4; ++r)
          O[(size_t)(rg + r) * DMODEL + cg] = (bf16)((acc[m][n][r] + bi) * qs);
      }
    }
  } else {
    // V: store transposed Vt[b][h][e][s]
#pragma unroll
    for (int n = 0; n < 4; ++n) {
      int ep = (col0 & 511) + wc * 64 + n * 16 + lr;
      int h = ep >> 6, e = ep & 63;
      float bi = bv[ep];
#pragma unroll
      for (int m = 0; m < 4; ++m) {
        int rg = row0 + wr * 64 + m * 16 + lg * 4;
        int b = rg >> 11, s0 = rg & 2047;
        bf16x4v pk;
#pragma unroll
        for (int r = 0; r < 4; ++r) pk[r] = (bf16)(acc[m][n][r] + bi);
        *(bf16x4v*)(Vt + ((size_t)((b * 8 + h) * 64 + e)) * S_LEN + s0) = pk;
      }
    }
  }
}

// Wo GEMM + bias + residual, bf16 out (LN reads bf16).
__global__ __launch_bounds__(256) void gemm_wo(
    const bf16* __restrict__ A, const bf16* __restrict__ W,
    const float* __restrict__ bo, const float* __restrict__ embed,
    bf16* __restrict__ X) {
  __shared__ __align__(16) bf16 As[128 * 64];
  __shared__ __align__(16) bf16 Bs[128 * 64];
  int row0 = blockIdx.x * 128, col0 = blockIdx.y * 128;
  f32x4 acc[4][4] = {};
  gemm128_core(A, W, row0, col0, As, Bs, acc);

  int tid = threadIdx.x;
  int w = tid >> 6, l = tid & 63, lr = l & 15, lg = l >> 4;
  int wr = w >> 1, wc = w & 1;
#pragma unroll
  for (int n = 0; n < 4; ++n) {
    int cg = col0 + wc * 64 + n * 16 + lr;
    float bi = bo[cg];
#pragma unroll
    for (int m = 0; m < 4; ++m) {
      int rg = row0 + wr * 64 + m * 16 + lg * 4;
#pragma unroll
      for (int r = 0; r < 4; ++r)
        X[(size_t)(rg + r) * DMODEL + cg] =
            (bf16)(acc[m][n][r] + bi + embed[(size_t)(rg + r) * DMODEL + cg]);
    }
  }
}

// SUF[bh][j][e] = sum_{t >= 16j} V[t][e], j = 0..128 (SUF[128]=0).
// 512 threads: 8 segments x 16 chunks; segmented suffix scan.
__global__ __launch_bounds__(512) void suf_kernel(const bf16* __restrict__ Vt,
                                                  float* __restrict__ SUF) {
  int bh = blockIdx.x;
  int e = threadIdx.x & 63;
  int seg = threadIdx.x >> 6;  // 0..7
  __shared__ float segtot[8][64];
  const bf16* vrow = Vt + ((size_t)bh * 64 + e) * S_LEN;
  float loc[16];
  float carry = 0.f;
#pragma unroll
  for (int j = 15; j >= 0; --j) {
    int jj = seg * 16 + j;
    bf16x8 a = *(const bf16x8*)(vrow + jj * 16);
    bf16x8 b2 = *(const bf16x8*)(vrow + jj * 16 + 8);
    float s = 0.f;
#pragma unroll
    for (int k = 0; k < 8; ++k) s += (float)a[k] + (float)b2[k];
    carry += s;
    loc[j] = carry;
  }
  segtot[seg][e] = carry;
  __syncthreads();
  float add = 0.f;
  for (int s2 = seg + 1; s2 < 8; ++s2) add += segtot[s2][e];
  float* srow = SUF + (size_t)bh * 129 * 64 + e;
#pragma unroll
  for (int j = 0; j < 16; ++j) srow[(size_t)(seg * 16 + j) * 64] = loc[j] + add;
  if (threadIdx.x < 64) srow[(size_t)128 * 64] = 0.f;
}

// Flash attention v3+setprio: 8 waves, waves 0-3 = big q-tile (16+p), waves 4-7 =
// small q-tile (15-p), one shared KV sweep (nt = 17+p), double-buffered GLDS
// staging, flat softmax via bare exp2.
__global__ __launch_bounds__(512) void flash_attn(
    const bf16* __restrict__ Qb, const bf16* __restrict__ Kb,
    const bf16* __restrict__ Vt, const float* __restrict__ SUF,
    bf16* __restrict__ attO) {
  int bh = blockIdx.y;
  int b = bh >> 3, h = bh & 7;
  int p = (int)gridDim.x - 1 - (int)blockIdx.x;  // 15..0, biggest first
  int tid = threadIdx.x;
  int w = tid >> 6, l = tid & 63, lr = l & 15, lg = l >> 4;
  int wsub = w & 3;
  int qtile = (w < 4) ? (16 + p) : (15 - p);
  int qb = qtile * 64;
  int nt = 17 + p;  // block-uniform KV-tile count (covers big tile's range)

  __shared__ __align__(16) bf16 kl[2][64 * 64];   // K tile [t][e], swizzled
  __shared__ __align__(16) bf16 vl[2][64 * 64];   // V^T tile [e][t], swizzled
  __shared__ __align__(16) bf16 pl[8][16 * 64];   // per-wave P tile [s][t], swizzled

  int srow = qb + 16 * wsub + lr;
  const bf16* qptr = Qb + ((size_t)(b * S_LEN) + srow) * DMODEL + h * 64 + lg * 8;
  bf16x8 aq0 = *(const bf16x8*)(qptr);
  bf16x8 aq1 = *(const bf16x8*)(qptr + 32);

  float lsum[4] = {0.f, 0.f, 0.f, 0.f};
  f32x4 acc[4] = {};

  int tmax_w = qb + 16 * wsub + 16;  // analytic tail starts here for this wave

  // staging: thread -> (row 0..63, chunk 0..7); source pre-swizzled chunk^=(row&7)
  int grow = tid >> 3, gch = tid & 7;
  int sch = ((gch ^ (grow & 7)) << 3);
  const bf16* Kg = Kb + ((size_t)(b * S_LEN) + grow) * DMODEL + h * 64 + sch;
  const bf16* Vg = Vt + ((size_t)(bh * 64) + grow) * S_LEN + sch;
  int sdst = w * 1024;  // wave-uniform LDS dest (lane*16 implicit)

  // fragment-read swizzle offsets
  int sw0 = (lg ^ (lr & 7)) << 4;
  int sw4 = sw0 ^ 0x40;
  char* plb = (char*)pl[w];

  // prologue: stage tile 0 into buf 0
  GLDS(Kg, (char*)kl[0] + sdst);
  GLDS(Vg, (char*)vl[0] + sdst);
  asm volatile("s_waitcnt vmcnt(0)" ::: "memory");
  __syncthreads();

  int cur = 0;
  for (int it = 0; it < nt; ++it) {
    int t0 = it << 6;
    if (it + 1 < nt) {
      GLDS(Kg + (size_t)(t0 + 64) * DMODEL, (char*)kl[cur ^ 1] + sdst);
      GLDS(Vg + (t0 + 64), (char*)vl[cur ^ 1] + sdst);
    }
    if (t0 < tmax_w) {  // wave-uniform skip of fully-masked tiles
      char* klb = (char*)kl[cur];
      char* vlb = (char*)vl[cur];

      f32x4 sfrag[4];
      const f32x4 fz = {0.f, 0.f, 0.f, 0.f};
      __builtin_amdgcn_s_setprio(1);
#pragma unroll
      for (int c = 0; c < 4; ++c) {
        int rb = (16 * c + lr) * 128;
        bf16x8 bk0 = *(const bf16x8*)(klb + rb + sw0);
        bf16x8 bk1 = *(const bf16x8*)(klb + rb + sw4);
        f32x4 t = __builtin_amdgcn_mfma_f32_16x16x32_bf16(aq0, bk0, fz, 0, 0, 0);
        sfrag[c] = __builtin_amdgcn_mfma_f32_16x16x32_bf16(aq1, bk1, t, 0, 0, 0);
      }
      __builtin_amdgcn_s_setprio(0);

      if (t0 + 64 <= qb + 16 * wsub) {
        // interior: no masking at all
#pragma unroll
        for (int r = 0; r < 4; ++r) {
          int row = lg * 4 + r;
          int pbase = row * 128 + ((lr & 7) << 1);
          int xorv = row & 7;
          float psum = 0.f;
#pragma unroll
          for (int c = 0; c < 4; ++c) {
            float pv = exp2f(sfrag[c][r]);
            psum += pv;
            int chunk = 2 * c + (lr >> 3);
            *(bf16*)(plb + pbase + (((chunk ^ xorv) << 4))) = (bf16)pv;
          }
          lsum[r] += psum;
        }
      } else {
        // boundary tile: per-element mask (x=0 inside tril-zero region, -inf past tail)
#pragma unroll
        for (int r = 0; r < 4; ++r) {
          int sg = qb + 16 * wsub + lg * 4 + r;
          int row = lg * 4 + r;
          int pbase = row * 128 + ((lr & 7) << 1);
          int xorv = row & 7;
          float psum = 0.f;
#pragma unroll
          for (int c = 0; c < 4; ++c) {
            int tg = t0 + 16 * c + lr;
            float x = (tg <= sg) ? sfrag[c][r] : ((tg < tmax_w) ? 0.f : -1e30f);
            float pv = exp2f(x);
            psum += pv;
            int chunk = 2 * c + (lr >> 3);
            *(bf16*)(plb + pbase + (((chunk ^ xorv) << 4))) = (bf16)pv;
          }
          lsum[r] += psum;
        }
      }

      bf16x8 pa0 = *(const bf16x8*)(plb + lr * 128 + sw0);
      bf16x8 pa1 = *(const bf16x8*)(plb + lr * 128 + sw4);
      __builtin_amdgcn_s_setprio(1);
#pragma unroll
      for (int c = 0; c < 4; ++c) {
        int rb = (16 * c + lr) * 128;
        bf16x8 bv0 = *(const bf16x8*)(vlb + rb + sw0);
        bf16x8 bv1 = *(const bf16x8*)(vlb + rb + sw4);
        acc[c] = __builtin_amdgcn_mfma_f32_16x16x32_bf16(pa0, bv0, acc[c], 0, 0, 0);
        acc[c] = __builtin_amdgcn_mfma_f32_16x16x32_bf16(pa1, bv1, acc[c], 0, 0, 0);
      }
      __builtin_amdgcn_s_setprio(0);
    }
    asm volatile("s_waitcnt vmcnt(0)" ::: "memory");
    __syncthreads();
    cur ^= 1;
  }

  // single end-of-kernel reduction of lsum across the 16 t-lanes
#pragma unroll
  for (int r = 0; r < 4; ++r) {
#pragma unroll
    for (int d = 1; d < 16; d <<= 1) lsum[r] += __shfl_xor(lsum[r], d, 64);
  }

  int j16 = tmax_w >> 4;
  const float* suf = SUF + ((size_t)bh * 129 + j16) * 64;
  float cnt = (float)(S_LEN - tmax_w);
  float sufe[4];
#pragma unroll
  for (int c = 0; c < 4; ++c) sufe[c] = suf[16 * c + lr];
#pragma unroll
  for (int r = 0; r < 4; ++r) {
    float inv = 1.f / (lsum[r] + cnt);
    int sg = qb + 16 * wsub + lg * 4 + r;
#pragma unroll
    for (int c = 0; c < 4; ++c) {
      float o = (acc[c][r] + sufe[c]) * inv;
      attO[((size_t)(b * S_LEN) + sg) * DMODEL + h * 64 + 16 * c + lr] = (bf16)o;
    }
  }
}

__global__ __launch_bounds__(256) void ln_kernel(const bf16* __restrict__ x,
                                                 const float* __restrict__ gamma,
                                                 const float* __restrict__ beta,
                                                 float* __restrict__ out) {
  int row = blockIdx.x * 4 + (threadIdx.x >> 6);
  int l = threadIdx.x & 63;
  bf16x8 xv = *(const bf16x8*)(x + (size_t)row * DMODEL + l * 8);
  float xf[8];
  float s = 0.f, s2 = 0.f;
#pragma unroll
  for (int k = 0; k < 8; ++k) {
    xf[k] = (float)xv[k];
    s += xf[k];
    s2 += xf[k] * xf[k];
  }
#pragma unroll
  for (int d = 1; d < 64; d <<= 1) {
    s += __shfl_xor(s, d, 64);
    s2 += __shfl_xor(s2, d, 64);
  }
  float mean = s * (1.f / 512.f);
  float var = s2 * (1.f / 512.f) - mean * mean;
  float rstd = rsqrtf(var + 1e-5f);
  const float4* g4 = reinterpret_cast<const float4*>(gamma) + l * 2;
  const float4* b4 = reinterpret_cast<const float4*>(beta) + l * 2;
  float4 g0 = g4[0], g1 = g4[1], bb0 = b4[0], bb1 = b4[1];
  float4 o0, o1;
  o0.x = (xf[0] - mean) * rstd * g0.x + bb0.x;
  o0.y = (xf[1] - mean) * rstd * g0.y + bb0.y;
  o0.z = (xf[2] - mean) * rstd * g0.z + bb0.z;
  o0.w = (xf[3] - mean) * rstd * g0.w + bb0.w;
  o1.x = (xf[4] - mean) * rstd * g1.x + bb1.x;
  o1.y = (xf[5] - mean) * rstd * g1.y + bb1.y;
  o1.z = (xf[6] - mean) * rstd * g1.z + bb1.z;
  o1.w = (xf[7] - mean) * rstd * g1.w + bb1.w;
  float4* orow = reinterpret_cast<float4*>(out + (size_t)row * DMODEL) + l * 2;
  orow[0] = o0;
  orow[1] = o1;
}

extern "C" void kernel_launch(void* const* d_in, const int* in_sizes, int n_in,
                              void* d_out, int out_size, void* d_ws, size_t ws_size,
                              hipStream_t stream) {
  const float* embed = (const float*)d_in[0];
  const float* Wq = (const float*)d_in[1];
  const float* bq = (const float*)d_in[2];
  const float* Wk = (const float*)d_in[3];
  const float* bk = (const float*)d_in[4];
  const float* Wv = (const float*)d_in[5];
  const float* bv = (const float*)d_in[6];
  const float* Wo = (const float*)d_in[7];
  const float* bo = (const float*)d_in[8];
  const float* gamma = (const float*)d_in[9];
  const float* beta = (const float*)d_in[10];
  float* out = (float*)d_out;

  char* ws = (char*)d_ws;
  size_t off = 0;
  auto alc = [&](size_t b) { size_t o = off; off += (b + 255) & ~(size_t)255; return o; };
  bf16* Eb    = (bf16*)(ws + alc(8192ull * 512 * 2));
  bf16* Wqkv  = (bf16*)(ws + alc(1536ull * 512 * 2));
  bf16* Wob   = (bf16*)(ws + alc(512ull * 512 * 2));
  bf16* Qb    = (bf16*)(ws + alc(8192ull * 512 * 2));
  bf16* Kb    = (bf16*)(ws + alc(8192ull * 512 * 2));
  bf16* Vt    = (bf16*)(ws + alc(8192ull * 512 * 2));
  float* SUF  = (float*)(ws + alc(32ull * 129 * 64 * 4));
  bf16* AttO  = (bf16*)(ws + alc(8192ull * 512 * 2));
  bf16* Xb    = (bf16*)(ws + alc(8192ull * 512 * 2));
  (void)ws_size; (void)n_in; (void)in_sizes; (void)out_size;

  cast_all<<<5120, 256, 0, stream>>>(embed, Wq, Wk, Wv, Wo, Eb, Wqkv, Wob);

  gemm_qkv<<<dim3(64, 12), 256, 0, stream>>>(Eb, Wqkv, bq, bk, bv, Qb, Kb, Vt);
  suf_kernel<<<32, 512, 0, stream>>>(Vt, SUF);
  flash_attn<<<dim3(16, 32), 512, 0, stream>>>(Qb, Kb, Vt, SUF, AttO);
  gemm_wo<<<dim3(64, 4), 256, 0, stream>>>(AttO, Wob, bo, embed, Xb);
  ln_kernel<<<2048, 256, 0, stream>>>(Xb, gamma, beta, out);
}